// Round 1
// baseline (339.596 us; speedup 1.0000x reference)
//
#include <hip/hip_runtime.h>

// SelfAttention fused pipeline for MI355X (gfx950), bf16 MFMA compute, f32 I/O.
//
//  K1  gemm_bt<0>: qkv = x @ w_qkv^T   (f32 in, on-the-fly bf16 cvt, MFMA 16x16x32)
//       epilogue scatters: Qb [b,h,l,d] (scaled 1/32), Kb [b,h,l,d], Vt [b,h,d,l]  (bf16, ws)
//  K2  attn_fwd: flash attention, 4 independent waves/block, 16 q-rows/wave, KV tile 64.
//       S = mfma(Q,K) frags straight from global (L2-resident); online softmax via
//       16-lane shfl reduces; P re-layout via per-wave padded LDS; O f32 [b,l,h*64+d] -> ws
//  K3  gemm_bt<1>: out = Of @ w_out^T + b_out  (f32 out)
//
// Workspace layout (bytes), total 41,943,040:
//   Qb @ 0         8,388,608
//   Kb @ 8388608   8,388,608
//   Vt @ 16777216  8,388,608
//   Of @ 25165824 16,777,216

typedef __bf16 bf16;
typedef __bf16 bf16x8 __attribute__((ext_vector_type(8)));
typedef float  f32x4 __attribute__((ext_vector_type(4)));

#define MFMA16(A, B, C) __builtin_amdgcn_mfma_f32_16x16x32_bf16((A), (B), (C), 0, 0, 0)

static constexpr int QOFF = 0;
static constexpr int KOFF = 8388608;
static constexpr int VOFF = 16777216;
static constexpr int OOFF = 25165824;

// C[M,N] = A[M,K] * B[N,K]^T, K=1024. 128x128 tile, BK=32, 4 waves (each 64x64).
// LDS pitch 40 bf16 (80 B): fragment ds_read_b128 is ~2-way (free) instead of 8-way.
template <int MODE> // 0: N=3072 qkv scatter epilogue; 1: N=1024 f32+bias epilogue
__global__ __launch_bounds__(256, 2)
void gemm_bt(const float* __restrict__ Ag, const float* __restrict__ Bg,
             float* __restrict__ outp, const float* __restrict__ bias,
             char* __restrict__ wsp)
{
  constexpr int K  = 1024;
  constexpr int NT = K / 32;
  const int bm = blockIdx.y, bn = blockIdx.x;
  const int tid  = threadIdx.x;
  const int lane = tid & 63;
  const int l15  = lane & 15, g = lane >> 4;
  const int wave = tid >> 6;
  const int wr = wave >> 1, wc = wave & 1;

  __shared__ __align__(16) bf16 Ab[2][128 * 40];
  __shared__ __align__(16) bf16 Bb[2][128 * 40];

  const int r  = tid >> 1;         // 0..127: LDS row this thread stages
  const int c0 = (tid & 1) * 16;   // 0 or 16: first k-col staged

  const float* ap = Ag + (bm * 128 + r) * K + c0;
  const float* bp = Bg + (bn * 128 + r) * K + c0;

  f32x4 areg[4], breg[4];
  f32x4 acc[4][4] = {};

  auto load_regs = [&](int t) {
#pragma unroll
    for (int i = 0; i < 4; ++i) {
      areg[i] = *(const f32x4*)(ap + t * 32 + i * 4);
      breg[i] = *(const f32x4*)(bp + t * 32 + i * 4);
    }
  };
  auto cvt_store = [&](int buf) {
#pragma unroll
    for (int half = 0; half < 2; ++half) {
      bf16x8 ta, tb;
#pragma unroll
      for (int j = 0; j < 8; ++j) {
        ta[j] = (bf16)areg[half * 2 + (j >> 2)][j & 3];
        tb[j] = (bf16)breg[half * 2 + (j >> 2)][j & 3];
      }
      *(bf16x8*)&Ab[buf][r * 40 + c0 + half * 8] = ta;
      *(bf16x8*)&Bb[buf][r * 40 + c0 + half * 8] = tb;
    }
  };

  load_regs(0);
  cvt_store(0);
  __syncthreads();

#pragma unroll 2
  for (int t = 0; t < NT; ++t) {
    if (t + 1 < NT) load_regs(t + 1);   // prefetch next tile while MFMAs run
    const int buf = t & 1;
    bf16x8 af[4], bfv[4];
#pragma unroll
    for (int mf = 0; mf < 4; ++mf)
      af[mf] = *(const bf16x8*)&Ab[buf][(wr * 64 + mf * 16 + l15) * 40 + g * 8];
#pragma unroll
    for (int nf = 0; nf < 4; ++nf)
      bfv[nf] = *(const bf16x8*)&Bb[buf][(wc * 64 + nf * 16 + l15) * 40 + g * 8];
#pragma unroll
    for (int mf = 0; mf < 4; ++mf)
#pragma unroll
      for (int nf = 0; nf < 4; ++nf)
        acc[mf][nf] = MFMA16(af[mf], bfv[nf], acc[mf][nf]);
    __syncthreads();
    if (t + 1 < NT) {
      cvt_store((t + 1) & 1);
      __syncthreads();
    }
  }

  // C/D layout (HW-verified): col = lane&15, row = (lane>>4)*4 + reg
  if constexpr (MODE == 0) {
    bf16* Qb = (bf16*)(wsp + QOFF);
    bf16* Kb = (bf16*)(wsp + KOFF);
    bf16* Vt = (bf16*)(wsp + VOFF);
#pragma unroll
    for (int nf = 0; nf < 4; ++nf) {
      const int colb = bn * 128 + wc * 64 + nf * 16 + l15; // e in [0,3072)
      const int s = colb >> 10;          // 0:q 1:k 2:v
      const int h = (colb >> 6) & 15;
      const int d = colb & 63;
#pragma unroll
      for (int mf = 0; mf < 4; ++mf) {
#pragma unroll
        for (int rr = 0; rr < 4; ++rr) {
          const int rowg = bm * 128 + wr * 64 + mf * 16 + g * 4 + rr;
          const int bb = rowg >> 11, li = rowg & 2047;
          const float v = acc[mf][nf][rr];
          if (s == 0)
            Qb[((bb * 16 + h) * 2048 + li) * 64 + d] = (bf16)(v * 0.03125f); // fold 1/sqrt(D)
          else if (s == 1)
            Kb[((bb * 16 + h) * 2048 + li) * 64 + d] = (bf16)v;
          else
            Vt[((bb * 16 + h) * 64 + d) * 2048 + li] = (bf16)v;             // transposed
        }
      }
    }
  } else {
#pragma unroll
    for (int nf = 0; nf < 4; ++nf) {
      const int colg = bn * 128 + wc * 64 + nf * 16 + l15;
      const float bv = bias[colg];
#pragma unroll
      for (int mf = 0; mf < 4; ++mf) {
#pragma unroll
        for (int rr = 0; rr < 4; ++rr) {
          const int rowg = bm * 128 + wr * 64 + mf * 16 + g * 4 + rr;
          outp[rowg * 1024 + colg] = acc[mf][nf][rr] + bv;
        }
      }
    }
  }
}

// Flash attention. grid = 32 (b,h) * 32 q-tiles; block = 256 (4 independent waves).
// Wave owns 16 q-rows; per KV tile of 64: 8 S-MFMAs, online softmax, 8 PV-MFMAs.
__global__ __launch_bounds__(256)
void attn_fwd(const bf16* __restrict__ Q, const bf16* __restrict__ K,
              const bf16* __restrict__ Vt, float* __restrict__ O)
{
  const int bh   = blockIdx.x >> 5;
  const int qt   = blockIdx.x & 31;
  const int lane = threadIdx.x & 63;
  const int wave = threadIdx.x >> 6;
  const int l15  = lane & 15, g = lane >> 4;

  const bf16* Qh = Q + bh * (2048 * 64);
  const bf16* Kh = K + bh * (2048 * 64);
  const bf16* Vh = Vt + bh * (64 * 2048);

  const int q0 = qt * 64 + wave * 16;

  // per-wave P buffer; pitch 80 bf16 (160 B) -> b128 reads 2-way (free)
  __shared__ __align__(16) bf16 Plds[4][16][80];

  bf16x8 qf[2];
#pragma unroll
  for (int ds = 0; ds < 2; ++ds)
    qf[ds] = *(const bf16x8*)(Qh + (q0 + l15) * 64 + ds * 32 + g * 8);

  f32x4 o[4] = {};
  float m[4]    = {-1e30f, -1e30f, -1e30f, -1e30f};
  float ssum[4] = {0.f, 0.f, 0.f, 0.f};

  for (int kb = 0; kb < 2048; kb += 64) {
    // ---- S = (Q*scale) K^T : 16q x 64k, acc over d in 2 steps
    f32x4 sf[4] = {};
#pragma unroll
    for (int kg = 0; kg < 4; ++kg) {
#pragma unroll
      for (int ds = 0; ds < 2; ++ds) {
        bf16x8 kf = *(const bf16x8*)(Kh + (kb + kg * 16 + l15) * 64 + ds * 32 + g * 8);
        sf[kg] = MFMA16(qf[ds], kf, sf[kg]);
      }
    }
    // ---- online softmax: row max over 64 cols (4 frags local + 16-lane shfl)
    float al[4];
#pragma unroll
    for (int rr = 0; rr < 4; ++rr) {
      float t = fmaxf(fmaxf(sf[0][rr], sf[1][rr]), fmaxf(sf[2][rr], sf[3][rr]));
      t = fmaxf(t, __shfl_xor(t, 1));
      t = fmaxf(t, __shfl_xor(t, 2));
      t = fmaxf(t, __shfl_xor(t, 4));
      t = fmaxf(t, __shfl_xor(t, 8));
      const float nm = fmaxf(m[rr], t);
      al[rr] = __expf(m[rr] - nm);
      m[rr]  = nm;
    }
    // ---- P = exp(S - m), stash bf16 in LDS (C-layout -> A-layout transpose)
    float rs[4] = {0.f, 0.f, 0.f, 0.f};
#pragma unroll
    for (int kg = 0; kg < 4; ++kg) {
#pragma unroll
      for (int rr = 0; rr < 4; ++rr) {
        const float p = __expf(sf[kg][rr] - m[rr]);
        rs[rr] += p;
        Plds[wave][g * 4 + rr][kg * 16 + l15] = (bf16)p;
      }
    }
#pragma unroll
    for (int rr = 0; rr < 4; ++rr) {
      float t = rs[rr];
      t += __shfl_xor(t, 1);
      t += __shfl_xor(t, 2);
      t += __shfl_xor(t, 4);
      t += __shfl_xor(t, 8);
      ssum[rr] = ssum[rr] * al[rr] + t;
    }
#pragma unroll
    for (int dg = 0; dg < 4; ++dg)
#pragma unroll
      for (int rr = 0; rr < 4; ++rr)
        o[dg][rr] *= al[rr];
    // ---- O += P @ V   (A-frag from Plds, B-frag contiguous thanks to Vt layout)
#pragma unroll
    for (int ks = 0; ks < 2; ++ks) {
      const bf16x8 pf = *(const bf16x8*)&Plds[wave][l15][ks * 32 + g * 8];
#pragma unroll
      for (int dg = 0; dg < 4; ++dg) {
        bf16x8 vf = *(const bf16x8*)(Vh + (dg * 16 + l15) * 2048 + kb + ks * 32 + g * 8);
        o[dg] = MFMA16(pf, vf, o[dg]);
      }
    }
  }

  const int b = bh >> 4, h = bh & 15;
#pragma unroll
  for (int dg = 0; dg < 4; ++dg) {
#pragma unroll
    for (int rr = 0; rr < 4; ++rr) {
      const int row = q0 + g * 4 + rr;
      O[(b * 2048 + row) * 1024 + h * 64 + dg * 16 + l15] = o[dg][rr] / ssum[rr];
    }
  }
}

extern "C" void kernel_launch(void* const* d_in, const int* in_sizes, int n_in,
                              void* d_out, int out_size, void* d_ws, size_t ws_size,
                              hipStream_t stream)
{
  (void)in_sizes; (void)n_in; (void)out_size; (void)ws_size;
  const float* x     = (const float*)d_in[0];
  const float* w_qkv = (const float*)d_in[1];
  const float* w_out = (const float*)d_in[2];
  const float* b_out = (const float*)d_in[3];
  float* out = (float*)d_out;
  char*  ws  = (char*)d_ws;

  bf16*  Qb = (bf16*)(ws + QOFF);
  bf16*  Kb = (bf16*)(ws + KOFF);
  bf16*  Vt = (bf16*)(ws + VOFF);
  float* Of = (float*)(ws + OOFF);

  gemm_bt<0><<<dim3(24, 32), 256, 0, stream>>>(x, w_qkv, nullptr, nullptr, ws);
  attn_fwd<<<dim3(1024), 256, 0, stream>>>(Qb, Kb, Vt, Of);
  gemm_bt<1><<<dim3(8, 32), 256, 0, stream>>>(Of, w_out, out, b_out, ws);
}

// Round 2
// 195.498 us; speedup vs baseline: 1.7371x; 1.7371x over previous
//
#include <hip/hip_runtime.h>

// SelfAttention fused pipeline for MI355X (gfx950), bf16 MFMA compute, f32 I/O.
//
//  K1  gemm_bt<0>: qkv = x @ w_qkv^T  (f32 in, bf16 cvt, MFMA 16x16x32)
//       epilogue scatters: Qb [bh,l,d] (scaled 1/32); Kb, Vw as SWIZZLED 8KB tile
//       images (64 rows x 8 chunks of 16B, chunk' = chunk ^ (row&7)) ready for
//       linear global_load_lds staging + conflict-free ds_read_b128 frags.
//  K2  attn_fwd: flash attention, 4 waves/block, 16 q-rows/wave, KV tile 64.
//       K/V cooperatively staged to LDS (K dbuf, V single + post-PV barrier);
//       XCD-swizzled grid so each (b,h)'s K/V stays in one XCD L2.
//  K3  gemm_bt<1>: out = Of @ w_out^T + b_out  (f32 out)

typedef __bf16 bf16;
typedef __bf16 bf16x8 __attribute__((ext_vector_type(8)));
typedef float  f32x4 __attribute__((ext_vector_type(4)));

#define MFMA16(A, B, C) __builtin_amdgcn_mfma_f32_16x16x32_bf16((A), (B), (C), 0, 0, 0)

static constexpr int QOFF = 0;
static constexpr int KOFF = 8388608;
static constexpr int VOFF = 16777216;
static constexpr int OOFF = 25165824;

__device__ __forceinline__ void gl16(const bf16* g, bf16* l) {
  __builtin_amdgcn_global_load_lds((const __attribute__((address_space(1))) void*)g,
                                   (__attribute__((address_space(3))) void*)l, 16, 0, 0);
}

// C[M,N] = A[M,K] * B[N,K]^T, K=1024. 128x128 tile, BK=32, 4 waves (each 64x64).
template <int MODE> // 0: N=3072 qkv scatter epilogue; 1: N=1024 f32+bias epilogue
__global__ __launch_bounds__(256, 2)
void gemm_bt(const float* __restrict__ Ag, const float* __restrict__ Bg,
             float* __restrict__ outp, const float* __restrict__ bias,
             char* __restrict__ wsp)
{
  constexpr int K  = 1024;
  constexpr int NT = K / 32;
  const int bm = blockIdx.y, bn = blockIdx.x;
  const int tid  = threadIdx.x;
  const int lane = tid & 63;
  const int l15  = lane & 15, g = lane >> 4;
  const int wave = tid >> 6;
  const int wr = wave >> 1, wc = wave & 1;

  __shared__ __align__(16) bf16 Ab[2][128 * 40];
  __shared__ __align__(16) bf16 Bb[2][128 * 40];

  const int r  = tid >> 1;
  const int c0 = (tid & 1) * 16;

  const float* ap = Ag + (bm * 128 + r) * K + c0;
  const float* bp = Bg + (bn * 128 + r) * K + c0;

  f32x4 areg[4], breg[4];
  f32x4 acc[4][4] = {};

  auto load_regs = [&](int t) {
#pragma unroll
    for (int i = 0; i < 4; ++i) {
      areg[i] = *(const f32x4*)(ap + t * 32 + i * 4);
      breg[i] = *(const f32x4*)(bp + t * 32 + i * 4);
    }
  };
  auto cvt_store = [&](int buf) {
#pragma unroll
    for (int half = 0; half < 2; ++half) {
      bf16x8 ta, tb;
#pragma unroll
      for (int j = 0; j < 8; ++j) {
        ta[j] = (bf16)areg[half * 2 + (j >> 2)][j & 3];
        tb[j] = (bf16)breg[half * 2 + (j >> 2)][j & 3];
      }
      *(bf16x8*)&Ab[buf][r * 40 + c0 + half * 8] = ta;
      *(bf16x8*)&Bb[buf][r * 40 + c0 + half * 8] = tb;
    }
  };

  load_regs(0);
  cvt_store(0);
  __syncthreads();

#pragma unroll 2
  for (int t = 0; t < NT; ++t) {
    if (t + 1 < NT) load_regs(t + 1);
    const int buf = t & 1;
    bf16x8 af[4], bfv[4];
#pragma unroll
    for (int mf = 0; mf < 4; ++mf)
      af[mf] = *(const bf16x8*)&Ab[buf][(wr * 64 + mf * 16 + l15) * 40 + g * 8];
#pragma unroll
    for (int nf = 0; nf < 4; ++nf)
      bfv[nf] = *(const bf16x8*)&Bb[buf][(wc * 64 + nf * 16 + l15) * 40 + g * 8];
#pragma unroll
    for (int mf = 0; mf < 4; ++mf)
#pragma unroll
      for (int nf = 0; nf < 4; ++nf)
        acc[mf][nf] = MFMA16(af[mf], bfv[nf], acc[mf][nf]);
    __syncthreads();
    if (t + 1 < NT) {
      cvt_store((t + 1) & 1);
      __syncthreads();
    }
  }

  // C/D layout: col = lane&15, row = (lane>>4)*4 + reg
  if constexpr (MODE == 0) {
    bf16* Qb = (bf16*)(wsp + QOFF);
    bf16* Kb = (bf16*)(wsp + KOFF);
    bf16* Vw = (bf16*)(wsp + VOFF);
#pragma unroll
    for (int nf = 0; nf < 4; ++nf) {
      const int colb = bn * 128 + wc * 64 + nf * 16 + l15; // e in [0,3072)
      const int s = colb >> 10;          // 0:q 1:k 2:v
      const int h = (colb >> 6) & 15;
      const int d = colb & 63;
#pragma unroll
      for (int mf = 0; mf < 4; ++mf) {
#pragma unroll
        for (int rr = 0; rr < 4; ++rr) {
          const int rowg = bm * 128 + wr * 64 + mf * 16 + g * 4 + rr;
          const int bb = rowg >> 11, li = rowg & 2047;
          const float v = acc[mf][nf][rr];
          if (s == 0) {
            Qb[((bb * 16 + h) * 2048 + li) * 64 + d] = (bf16)(v * 0.03125f);
          } else if (s == 1) {
            const int sw = (((d >> 3) ^ (li & 7)) << 3) | (d & 7);
            Kb[((bb * 16 + h) * 2048 + li) * 64 + sw] = (bf16)v;
          } else {
            const int lc = li & 63;
            const int sw = (((lc >> 3) ^ (d & 7)) << 3) | (lc & 7);
            Vw[(bb * 16 + h) * 131072 + (li >> 6) * 4096 + d * 64 + sw] = (bf16)v;
          }
        }
      }
    }
  } else {
#pragma unroll
    for (int nf = 0; nf < 4; ++nf) {
      const int colg = bn * 128 + wc * 64 + nf * 16 + l15;
      const float bv = bias[colg];
#pragma unroll
      for (int mf = 0; mf < 4; ++mf) {
#pragma unroll
        for (int rr = 0; rr < 4; ++rr) {
          const int rowg = bm * 128 + wr * 64 + mf * 16 + g * 4 + rr;
          outp[rowg * 1024 + colg] = acc[mf][nf][rr] + bv;
        }
      }
    }
  }
}

// Flash attention. grid = 1024; XCD-swizzle: xcd = bh>>2 so one (b,h)'s K/V
// (512KB) is L2-resident on a single XCD. 4 waves/block, wave owns 16 q-rows.
__global__ __launch_bounds__(256)
void attn_fwd(const bf16* __restrict__ Q, const bf16* __restrict__ Kw,
              const bf16* __restrict__ Vw, float* __restrict__ O)
{
  const int bid  = blockIdx.x;
  const int slot = bid >> 3;
  const int bh   = (bid & 7) * 4 + (slot >> 5);
  const int qt   = slot & 31;
  const int lane = threadIdx.x & 63;
  const int wave = threadIdx.x >> 6;
  const int l15  = lane & 15, g = lane >> 4;

  const bf16* Qh = Q  + bh * (2048 * 64);
  const bf16* Ks = Kw + bh * (2048 * 64);   // 32 swizzled 4096-elem tile images
  const bf16* Vs = Vw + bh * (2048 * 64);

  __shared__ __align__(16) bf16 Klds[2][4096];
  __shared__ __align__(16) bf16 Vlds[4096];
  __shared__ __align__(16) bf16 Plds[4][16][80];

  const int q0 = qt * 64 + wave * 16;

  bf16x8 qf[2];
#pragma unroll
  for (int ds = 0; ds < 2; ++ds)
    qf[ds] = *(const bf16x8*)(Qh + (q0 + l15) * 64 + ds * 32 + g * 8);

  // stage one 8KB tile: 8 x (64 lanes x 16B); wave w issues chunks 2w, 2w+1
  auto stageK = [&](int t, int buf) {
    const bf16* s = Ks + t * 4096 + wave * 1024 + lane * 8;
#pragma unroll
    for (int j = 0; j < 2; ++j)
      gl16(s + j * 512, &Klds[buf][wave * 1024 + j * 512]);
  };
  auto stageV = [&](int t) {
    const bf16* s = Vs + t * 4096 + wave * 1024 + lane * 8;
#pragma unroll
    for (int j = 0; j < 2; ++j)
      gl16(s + j * 512, &Vlds[wave * 1024 + j * 512]);
  };

  f32x4 o[4] = {};
  float m[4]  = {-1e30f, -1e30f, -1e30f, -1e30f};
  float ps[4] = {0.f, 0.f, 0.f, 0.f};

  stageK(0, 0);
  stageV(0);
  __syncthreads();   // drain: K(0), V(0) ready

  for (int t = 0; t < 32; ++t) {
    const int cur = t & 1;
    if (t < 31) stageK(t + 1, cur ^ 1);   // lands by next step's pre-PV barrier

    // ---- S = (Q*scale) K^T : frags from swizzled LDS (conflict-balanced)
    f32x4 sf[4] = {};
#pragma unroll
    for (int kg = 0; kg < 4; ++kg) {
#pragma unroll
      for (int ds = 0; ds < 2; ++ds) {
        const bf16x8 kf = *(const bf16x8*)
          &Klds[cur][(kg * 16 + l15) * 64 + (((ds * 4 + g) ^ (l15 & 7)) << 3)];
        sf[kg] = MFMA16(qf[ds], kf, sf[kg]);
      }
    }

    // ---- online softmax: row max via 4-step shfl; sums kept per-lane (deferred)
    float al[4];
#pragma unroll
    for (int rr = 0; rr < 4; ++rr) {
      float tm = fmaxf(fmaxf(sf[0][rr], sf[1][rr]), fmaxf(sf[2][rr], sf[3][rr]));
      tm = fmaxf(tm, __shfl_xor(tm, 1));
      tm = fmaxf(tm, __shfl_xor(tm, 2));
      tm = fmaxf(tm, __shfl_xor(tm, 4));
      tm = fmaxf(tm, __shfl_xor(tm, 8));
      const float nm = fmaxf(m[rr], tm);
      al[rr] = __expf(m[rr] - nm);
      m[rr]  = nm;
    }
#pragma unroll
    for (int rr = 0; rr < 4; ++rr) {
      float rsl = 0.f;
#pragma unroll
      for (int kg = 0; kg < 4; ++kg) {
        const float p = __expf(sf[kg][rr] - m[rr]);
        rsl += p;
        Plds[wave][g * 4 + rr][kg * 16 + l15] = (bf16)p;
      }
      ps[rr] = ps[rr] * al[rr] + rsl;
#pragma unroll
      for (int dg = 0; dg < 4; ++dg) o[dg][rr] *= al[rr];
    }

    __syncthreads();   // drain: V(t) staged (+K(t+1)); all waves past S-reads

    // ---- O += P @ V
#pragma unroll
    for (int ks = 0; ks < 2; ++ks) {
      const bf16x8 pf = *(const bf16x8*)&Plds[wave][l15][ks * 32 + g * 8];
#pragma unroll
      for (int dg = 0; dg < 4; ++dg) {
        const bf16x8 vf = *(const bf16x8*)
          &Vlds[(dg * 16 + l15) * 64 + (((ks * 4 + g) ^ (l15 & 7)) << 3)];
        o[dg] = MFMA16(pf, vf, o[dg]);
      }
    }
    __syncthreads();   // all PV reads of V(t) done
    if (t < 31) stageV(t + 1);
  }

  // deferred denominator: one cross-lane reduce at the end
  const int b = bh >> 4, h = bh & 15;
#pragma unroll
  for (int rr = 0; rr < 4; ++rr) {
    float s = ps[rr];
    s += __shfl_xor(s, 1);
    s += __shfl_xor(s, 2);
    s += __shfl_xor(s, 4);
    s += __shfl_xor(s, 8);
    const float inv = 1.f / s;
#pragma unroll
    for (int dg = 0; dg < 4; ++dg) {
      const int row = q0 + g * 4 + rr;
      O[(b * 2048 + row) * 1024 + h * 64 + dg * 16 + l15] = o[dg][rr] * inv;
    }
  }
}

extern "C" void kernel_launch(void* const* d_in, const int* in_sizes, int n_in,
                              void* d_out, int out_size, void* d_ws, size_t ws_size,
                              hipStream_t stream)
{
  (void)in_sizes; (void)n_in; (void)out_size; (void)ws_size;
  const float* x     = (const float*)d_in[0];
  const float* w_qkv = (const float*)d_in[1];
  const float* w_out = (const float*)d_in[2];
  const float* b_out = (const float*)d_in[3];
  float* out = (float*)d_out;
  char*  ws  = (char*)d_ws;

  bf16*  Qb = (bf16*)(ws + QOFF);
  bf16*  Kb = (bf16*)(ws + KOFF);
  bf16*  Vw = (bf16*)(ws + VOFF);
  float* Of = (float*)(ws + OOFF);

  gemm_bt<0><<<dim3(24, 32), 256, 0, stream>>>(x, w_qkv, nullptr, nullptr, ws);
  attn_fwd<<<dim3(1024), 256, 0, stream>>>(Qb, Kb, Vw, Of);
  gemm_bt<1><<<dim3(8, 32), 256, 0, stream>>>(Of, w_out, out, b_out, ws);
}

// Round 3
// 142.207 us; speedup vs baseline: 2.3880x; 1.3747x over previous
//
#include <hip/hip_runtime.h>

// SelfAttention fused pipeline, MI355X gfx950. bf16 MFMA compute, f32 I/O.
//
//  K0  cvt_bf16 x3: x, w_qkv, w_out -> bf16 workspace copies
//  K1  gemm_bt<0>: qkv = xb @ w_qkvb^T; epilogue scatters Qb (x 1/32*log2e),
//      Kb and Vw as swizzled 8KB tile images (16B chunks XOR'd by row&7)
//  K2  attn_fwd: flash attn; swapped QK^T (lane owns one q-row: 2-shfl max,
//      per-lane m/ps), PV via v_mfma 16x16x16 consuming P in-register,
//      K/V both LDS-double-buffered, ONE barrier per KV tile, defer-max.
//      Writes Of bf16 [4096][1024].
//  K3  gemm_bt<1>: out = Of @ w_outb^T + b_out  (f32 out)
//
// ws: [Qb 8M][Kb 8M][Vw 8M][xb|Of 8M][wqkvb 6M][woutb 2M] = 40 MB

typedef __bf16 bf16;
typedef __bf16 bf16x4 __attribute__((ext_vector_type(4)));
typedef __bf16 bf16x8 __attribute__((ext_vector_type(8)));
typedef float  f32x4 __attribute__((ext_vector_type(4)));

#define MFMA32(A, B, C) __builtin_amdgcn_mfma_f32_16x16x32_bf16((A), (B), (C), 0, 0, 0)

static constexpr long QOFF  = 0;
static constexpr long KOFF  = 8388608;
static constexpr long VOFF  = 16777216;
static constexpr long FOFF  = 25165824;   // xb during gemm0, Of afterwards
static constexpr long WQOFF = 33554432;
static constexpr long WOOFF = 39845888;

// q scale: 1/sqrt(1024) * log2(e)  (softmax done in exp2 domain)
#define QSCALE 0.045084222f

__device__ __forceinline__ void gl16(const bf16* g, bf16* l) {
  __builtin_amdgcn_global_load_lds((const __attribute__((address_space(1))) void*)g,
                                   (__attribute__((address_space(3))) void*)l, 16, 0, 0);
}

__device__ __forceinline__ f32x4 mfma16(bf16x4 a, bf16x4 b, f32x4 c) {
  asm("v_mfma_f32_16x16x16_bf16 %0, %1, %2, %0" : "+v"(c) : "v"(a), "v"(b));
  return c;
}

__device__ __forceinline__ float exp2fast(float x) {
#if __has_builtin(__builtin_amdgcn_exp2f)
  return __builtin_amdgcn_exp2f(x);
#else
  return exp2f(x);
#endif
}

__global__ __launch_bounds__(256)
void cvt_bf16(const float* __restrict__ in, bf16* __restrict__ out, int n8) {
  const int i = blockIdx.x * 256 + threadIdx.x;
  if (i < n8) {
    const f32x4 v0 = *(const f32x4*)(in + (long)i * 8);
    const f32x4 v1 = *(const f32x4*)(in + (long)i * 8 + 4);
    bf16x8 o;
#pragma unroll
    for (int j = 0; j < 4; ++j) { o[j] = (bf16)v0[j]; o[j + 4] = (bf16)v1[j]; }
    *(bf16x8*)(out + (long)i * 8) = o;
  }
}

// C[M,N] = A[M,K] * B[N,K]^T, K=1024, bf16 inputs. 128x128 tile, BK=32, 4 waves.
template <int MODE> // 0: qkv scatter epilogue; 1: f32+bias epilogue
__global__ __launch_bounds__(256, 2)
void gemm_bt(const bf16* __restrict__ Ag, const bf16* __restrict__ Bg,
             float* __restrict__ outp, const float* __restrict__ bias,
             char* __restrict__ wsp)
{
  constexpr int K  = 1024;
  constexpr int NT = K / 32;
  const int bm = blockIdx.y, bn = blockIdx.x;
  const int tid  = threadIdx.x;
  const int lane = tid & 63;
  const int l15  = lane & 15, g = lane >> 4;
  const int wave = tid >> 6;
  const int wr = wave >> 1, wc = wave & 1;

  __shared__ __align__(16) bf16 Ab[2][128 * 40];
  __shared__ __align__(16) bf16 Bb[2][128 * 40];

  const int r  = tid >> 1;
  const int c0 = (tid & 1) * 16;

  const bf16* ap = Ag + (long)(bm * 128 + r) * K + c0;
  const bf16* bp = Bg + (long)(bn * 128 + r) * K + c0;

  bf16x8 a0, a1, b0, b1;
  f32x4 acc[4][4] = {};

  auto load_regs = [&](int t) {
    a0 = *(const bf16x8*)(ap + t * 32);
    a1 = *(const bf16x8*)(ap + t * 32 + 8);
    b0 = *(const bf16x8*)(bp + t * 32);
    b1 = *(const bf16x8*)(bp + t * 32 + 8);
  };
  auto store_lds = [&](int buf) {
    *(bf16x8*)&Ab[buf][r * 40 + c0]     = a0;
    *(bf16x8*)&Ab[buf][r * 40 + c0 + 8] = a1;
    *(bf16x8*)&Bb[buf][r * 40 + c0]     = b0;
    *(bf16x8*)&Bb[buf][r * 40 + c0 + 8] = b1;
  };

  load_regs(0);
  store_lds(0);
  __syncthreads();

#pragma unroll 2
  for (int t = 0; t < NT; ++t) {
    if (t + 1 < NT) load_regs(t + 1);
    const int buf = t & 1;
    bf16x8 af[4], bfv[4];
#pragma unroll
    for (int mf = 0; mf < 4; ++mf)
      af[mf] = *(const bf16x8*)&Ab[buf][(wr * 64 + mf * 16 + l15) * 40 + g * 8];
#pragma unroll
    for (int nf = 0; nf < 4; ++nf)
      bfv[nf] = *(const bf16x8*)&Bb[buf][(wc * 64 + nf * 16 + l15) * 40 + g * 8];
#pragma unroll
    for (int mf = 0; mf < 4; ++mf)
#pragma unroll
      for (int nf = 0; nf < 4; ++nf)
        acc[mf][nf] = MFMA32(af[mf], bfv[nf], acc[mf][nf]);
    __syncthreads();
    if (t + 1 < NT) {
      store_lds((t + 1) & 1);
      __syncthreads();
    }
  }

  // C/D layout: col = lane&15, row = (lane>>4)*4 + reg
  if constexpr (MODE == 0) {
    bf16* Qb = (bf16*)(wsp + QOFF);
    bf16* Kb = (bf16*)(wsp + KOFF);
    bf16* Vw = (bf16*)(wsp + VOFF);
#pragma unroll
    for (int nf = 0; nf < 4; ++nf) {
      const int colb = bn * 128 + wc * 64 + nf * 16 + l15; // e in [0,3072)
      const int s = colb >> 10;          // 0:q 1:k 2:v
      const int h = (colb >> 6) & 15;
      const int d = colb & 63;
#pragma unroll
      for (int mf = 0; mf < 4; ++mf) {
#pragma unroll
        for (int rr = 0; rr < 4; ++rr) {
          const int rowg = bm * 128 + wr * 64 + mf * 16 + g * 4 + rr;
          const int bb = rowg >> 11, li = rowg & 2047;
          const float v = acc[mf][nf][rr];
          if (s == 0) {
            Qb[(long)((bb * 16 + h) * 2048 + li) * 64 + d] = (bf16)(v * QSCALE);
          } else if (s == 1) {
            const int sw = (((d >> 3) ^ (li & 7)) << 3) | (d & 7);
            Kb[(long)((bb * 16 + h) * 2048 + li) * 64 + sw] = (bf16)v;
          } else {
            const int lc = li & 63;
            const int sw = (((lc >> 3) ^ (d & 7)) << 3) | (lc & 7);
            Vw[(long)(bb * 16 + h) * 131072 + (li >> 6) * 4096 + d * 64 + sw] = (bf16)v;
          }
        }
      }
    }
  } else {
#pragma unroll
    for (int nf = 0; nf < 4; ++nf) {
      const int colg = bn * 128 + wc * 64 + nf * 16 + l15;
      const float bv = bias[colg];
#pragma unroll
      for (int mf = 0; mf < 4; ++mf) {
#pragma unroll
        for (int rr = 0; rr < 4; ++rr) {
          const int rowg = bm * 128 + wr * 64 + mf * 16 + g * 4 + rr;
          outp[(long)rowg * 1024 + colg] = acc[mf][nf][rr] + bv;
        }
      }
    }
  }
}

// Flash attention, swapped-operand form. grid 1024 (XCD-swizzled), 4 waves.
// Lane owns q = l15; S'[k][q] via mfma(K,Q); P stays in registers for PV
// (v_mfma 16x16x16: B-frag kdim = g*4+j matches S' C-layout rows exactly).
__global__ __launch_bounds__(256, 4)
void attn_fwd(const bf16* __restrict__ Q, const bf16* __restrict__ Kw,
              const bf16* __restrict__ Vw, bf16* __restrict__ Of)
{
  const int bid  = blockIdx.x;
  const int slot = bid >> 3;
  const int bh   = (bid & 7) * 4 + (slot >> 5);
  const int qt   = slot & 31;
  const int lane = threadIdx.x & 63;
  const int wave = threadIdx.x >> 6;
  const int l15  = lane & 15, g = lane >> 4;

  const bf16* Qh = Q  + (long)bh * 131072;
  const bf16* Ks = Kw + (long)bh * 131072;
  const bf16* Vs = Vw + (long)bh * 131072;

  __shared__ __align__(16) bf16 Klds[2][4096];
  __shared__ __align__(16) bf16 Vlds[2][4096];

  const int q0 = qt * 64 + wave * 16;

  bf16x8 qf[2];
#pragma unroll
  for (int ds = 0; ds < 2; ++ds)
    qf[ds] = *(const bf16x8*)(Qh + (q0 + l15) * 64 + ds * 32 + g * 8);

  auto stage = [&](int t, int buf) {
    const bf16* sk = Ks + t * 4096 + wave * 1024 + lane * 8;
    const bf16* sv = Vs + t * 4096 + wave * 1024 + lane * 8;
    gl16(sk,       &Klds[buf][wave * 1024]);
    gl16(sk + 512, &Klds[buf][wave * 1024 + 512]);
    gl16(sv,       &Vlds[buf][wave * 1024]);
    gl16(sv + 512, &Vlds[buf][wave * 1024 + 512]);
  };

  f32x4 o[4] = {};
  float m = -1e30f, ps = 0.f;

  stage(0, 0);
  __syncthreads();

  for (int t = 0; t < 32; ++t) {
    const int cur = t & 1;
    if (t < 31) stage(t + 1, cur ^ 1);

    // ---- S'[k][q] : A = K-rows (swizzled LDS), B = Q (registers)
    f32x4 sf[4] = {};
#pragma unroll
    for (int kg = 0; kg < 4; ++kg) {
#pragma unroll
      for (int ds = 0; ds < 2; ++ds) {
        const bf16x8 kf = *(const bf16x8*)
          &Klds[cur][(kg * 16 + l15) * 64 + (((ds * 4 + g) ^ (l15 & 7)) << 3)];
        sf[kg] = MFMA32(kf, qf[ds], sf[kg]);
      }
    }

    // ---- per-lane softmax for q = l15 (2 shfls only)
    float tm = fmaxf(fmaxf(fmaxf(sf[0][0], sf[0][1]), fmaxf(sf[0][2], sf[0][3])),
                     fmaxf(fmaxf(sf[1][0], sf[1][1]), fmaxf(sf[1][2], sf[1][3])));
    tm = fmaxf(tm, fmaxf(fmaxf(fmaxf(sf[2][0], sf[2][1]), fmaxf(sf[2][2], sf[2][3])),
                         fmaxf(fmaxf(sf[3][0], sf[3][1]), fmaxf(sf[3][2], sf[3][3]))));
    tm = fmaxf(tm, __shfl_xor(tm, 16));
    tm = fmaxf(tm, __shfl_xor(tm, 32));

    if (!__all(tm <= m + 8.f)) {        // defer-max: rescale only on real growth
      const float nm = fmaxf(m, tm);
      const float al = exp2fast(m - nm);
      m = nm;
      ps *= al;
#pragma unroll
      for (int dg = 0; dg < 4; ++dg)
#pragma unroll
        for (int rr = 0; rr < 4; ++rr) o[dg][rr] *= al;
    }

    bf16x4 pa[4];
    float rs0 = 0.f, rs1 = 0.f, rs2 = 0.f, rs3 = 0.f;
#pragma unroll
    for (int kg = 0; kg < 4; ++kg) {
      const float p0 = exp2fast(sf[kg][0] - m);
      const float p1 = exp2fast(sf[kg][1] - m);
      const float p2 = exp2fast(sf[kg][2] - m);
      const float p3 = exp2fast(sf[kg][3] - m);
      rs0 += p0; rs1 += p1; rs2 += p2; rs3 += p3;
      pa[kg][0] = (bf16)p0; pa[kg][1] = (bf16)p1;
      pa[kg][2] = (bf16)p2; pa[kg][3] = (bf16)p3;
    }
    ps += (rs0 + rs1) + (rs2 + rs3);

    // ---- O'[d][q] += V^T-frag * P-frag   (16x16x16, P in-register)
#pragma unroll
    for (int kg = 0; kg < 4; ++kg) {
#pragma unroll
      for (int dg = 0; dg < 4; ++dg) {
        const bf16x4 vb = *(const bf16x4*)
          &Vlds[cur][(dg * 16 + l15) * 64 +
                     (((2 * kg + (g >> 1)) ^ (l15 & 7)) << 3) + ((g & 1) << 2)];
        o[dg] = mfma16(vb, pa[kg], o[dg]);
      }
    }
    __syncthreads();   // all reads of buf `cur` done; stages into cur^1 drained
  }

  ps += __shfl_xor(ps, 16);
  ps += __shfl_xor(ps, 32);
  const float inv = 1.f / ps;

  const int b = bh >> 4, h = bh & 15;
#pragma unroll
  for (int dg = 0; dg < 4; ++dg) {
    bf16x4 ov;
#pragma unroll
    for (int rr = 0; rr < 4; ++rr) ov[rr] = (bf16)(o[dg][rr] * inv);
    *(bf16x4*)(Of + (long)(b * 2048 + q0 + l15) * 1024 + h * 64 + dg * 16 + g * 4) = ov;
  }
}

extern "C" void kernel_launch(void* const* d_in, const int* in_sizes, int n_in,
                              void* d_out, int out_size, void* d_ws, size_t ws_size,
                              hipStream_t stream)
{
  (void)in_sizes; (void)n_in; (void)out_size; (void)ws_size;
  const float* x     = (const float*)d_in[0];
  const float* w_qkv = (const float*)d_in[1];
  const float* w_out = (const float*)d_in[2];
  const float* b_out = (const float*)d_in[3];
  float* out = (float*)d_out;
  char*  ws  = (char*)d_ws;

  bf16* Qb  = (bf16*)(ws + QOFF);
  bf16* Kb  = (bf16*)(ws + KOFF);
  bf16* Vw  = (bf16*)(ws + VOFF);
  bf16* xb  = (bf16*)(ws + FOFF);
  bf16* Ofb = (bf16*)(ws + FOFF);   // reuses xb region after gemm0 completes
  bf16* wqb = (bf16*)(ws + WQOFF);
  bf16* wob = (bf16*)(ws + WOOFF);

  cvt_bf16<<<dim3(2048), 256, 0, stream>>>(x, xb, 524288);
  cvt_bf16<<<dim3(1536), 256, 0, stream>>>(w_qkv, wqb, 393216);
  cvt_bf16<<<dim3(512),  256, 0, stream>>>(w_out, wob, 131072);

  gemm_bt<0><<<dim3(24, 32), 256, 0, stream>>>(xb, wqb, nullptr, nullptr, ws);
  attn_fwd<<<dim3(1024), 256, 0, stream>>>(Qb, Kb, Vw, Ofb);
  gemm_bt<1><<<dim3(8, 32), 256, 0, stream>>>(Ofb, wob, out, b_out, ws);
}

// Round 6
// 137.413 us; speedup vs baseline: 2.4714x; 1.0349x over previous
//
#include <hip/hip_runtime.h>

// SelfAttention fused pipeline, MI355X gfx950. bf16 MFMA compute, f32 I/O.
// ROUND 6 = exact round-3 proven kernels (attn 4-wave, gemm 128x128) with ONE
// delta: the three cvt dispatches fused into cvt_all. Bisect round after two
// failures localized the bug to {8-wave attn restructure | cvt_all}.
//
//  K0  cvt_all: x, w_qkv, w_out -> bf16 (one dispatch)
//  K1  gemm_bt<0>: qkv = xb @ wqb^T; epilogue scatters Qb (x scale*log2e),
//      Kb/Vw as swizzled 8KB tile images (16B chunk XOR'd by row&7)
//  K2  attn_fwd: flash attn, 4 waves x 16 q-rows, KV tile 64 double-buffered
//      via global_load_lds; online softmax w/ defer-max; P in-register into
//      v_mfma 16x16x16 PV.  (byte-identical to round 3's passing version)
//  K3  gemm_bt<1>: out = Of @ wob^T + b_out  (f32 out)
//
// ws: [Qb 8M][Kb 8M][Vw 8M][xb|Of 8M][wqb 6M][wob 2M] = 40 MB

typedef __bf16 bf16;
typedef __bf16 bf16x4 __attribute__((ext_vector_type(4)));
typedef __bf16 bf16x8 __attribute__((ext_vector_type(8)));
typedef float  f32x4 __attribute__((ext_vector_type(4)));

#define MFMA32(A, B, C) __builtin_amdgcn_mfma_f32_16x16x32_bf16((A), (B), (C), 0, 0, 0)

static constexpr long QOFF  = 0;
static constexpr long KOFF  = 8388608;
static constexpr long VOFF  = 16777216;
static constexpr long FOFF  = 25165824;   // xb during gemm0, Of afterwards
static constexpr long WQOFF = 33554432;
static constexpr long WOOFF = 39845888;

// q scale: 1/sqrt(1024) * log2(e)  (softmax in exp2 domain)
#define QSCALE 0.045084222f

__device__ __forceinline__ void gl16(const bf16* g, bf16* l) {
  __builtin_amdgcn_global_load_lds((const __attribute__((address_space(1))) void*)g,
                                   (__attribute__((address_space(3))) void*)l, 16, 0, 0);
}

__device__ __forceinline__ f32x4 mfma16(bf16x4 a, bf16x4 b, f32x4 c) {
  asm("v_mfma_f32_16x16x16_bf16 %0, %1, %2, %0" : "+v"(c) : "v"(a), "v"(b));
  return c;
}

__device__ __forceinline__ float exp2fast(float x) {
#if __has_builtin(__builtin_amdgcn_exp2f)
  return __builtin_amdgcn_exp2f(x);
#else
  return exp2f(x);
#endif
}

// one dispatch: 1048576 chunks of 8 f32 -> bf16
__global__ __launch_bounds__(256)
void cvt_all(const float* __restrict__ x, const float* __restrict__ wq,
             const float* __restrict__ wo, bf16* __restrict__ xb,
             bf16* __restrict__ wqb, bf16* __restrict__ wob) {
  const int i = blockIdx.x * 256 + threadIdx.x;
  const float* in; bf16* out; long j;
  if (i < 524288)      { in = x;  out = xb;  j = i; }
  else if (i < 917504) { in = wq; out = wqb; j = i - 524288; }
  else                 { in = wo; out = wob; j = i - 917504; }
  const f32x4 v0 = *(const f32x4*)(in + j * 8);
  const f32x4 v1 = *(const f32x4*)(in + j * 8 + 4);
  bf16x8 o;
#pragma unroll
  for (int k = 0; k < 4; ++k) { o[k] = (bf16)v0[k]; o[k + 4] = (bf16)v1[k]; }
  *(bf16x8*)(out + j * 8) = o;
}

// C[M,N] = A[M,K] * B[N,K]^T, K=1024, bf16 inputs. 128x128 tile, BK=32, 4 waves.
template <int MODE> // 0: qkv scatter epilogue; 1: f32+bias epilogue
__global__ __launch_bounds__(256, 2)
void gemm_bt(const bf16* __restrict__ Ag, const bf16* __restrict__ Bg,
             float* __restrict__ outp, const float* __restrict__ bias,
             char* __restrict__ wsp)
{
  constexpr int K  = 1024;
  constexpr int NT = K / 32;
  const int bm = blockIdx.y, bn = blockIdx.x;
  const int tid  = threadIdx.x;
  const int lane = tid & 63;
  const int l15  = lane & 15, g = lane >> 4;
  const int wave = tid >> 6;
  const int wr = wave >> 1, wc = wave & 1;

  __shared__ __align__(16) bf16 Ab[2][128 * 40];
  __shared__ __align__(16) bf16 Bb[2][128 * 40];

  const int r  = tid >> 1;
  const int c0 = (tid & 1) * 16;

  const bf16* ap = Ag + (long)(bm * 128 + r) * K + c0;
  const bf16* bp = Bg + (long)(bn * 128 + r) * K + c0;

  bf16x8 a0, a1, b0, b1;
  f32x4 acc[4][4] = {};

  auto load_regs = [&](int t) {
    a0 = *(const bf16x8*)(ap + t * 32);
    a1 = *(const bf16x8*)(ap + t * 32 + 8);
    b0 = *(const bf16x8*)(bp + t * 32);
    b1 = *(const bf16x8*)(bp + t * 32 + 8);
  };
  auto store_lds = [&](int buf) {
    *(bf16x8*)&Ab[buf][r * 40 + c0]     = a0;
    *(bf16x8*)&Ab[buf][r * 40 + c0 + 8] = a1;
    *(bf16x8*)&Bb[buf][r * 40 + c0]     = b0;
    *(bf16x8*)&Bb[buf][r * 40 + c0 + 8] = b1;
  };

  load_regs(0);
  store_lds(0);
  __syncthreads();

#pragma unroll 2
  for (int t = 0; t < NT; ++t) {
    if (t + 1 < NT) load_regs(t + 1);
    const int buf = t & 1;
    bf16x8 af[4], bfv[4];
#pragma unroll
    for (int mf = 0; mf < 4; ++mf)
      af[mf] = *(const bf16x8*)&Ab[buf][(wr * 64 + mf * 16 + l15) * 40 + g * 8];
#pragma unroll
    for (int nf = 0; nf < 4; ++nf)
      bfv[nf] = *(const bf16x8*)&Bb[buf][(wc * 64 + nf * 16 + l15) * 40 + g * 8];
#pragma unroll
    for (int mf = 0; mf < 4; ++mf)
#pragma unroll
      for (int nf = 0; nf < 4; ++nf)
        acc[mf][nf] = MFMA32(af[mf], bfv[nf], acc[mf][nf]);
    __syncthreads();
    if (t + 1 < NT) {
      store_lds((t + 1) & 1);
      __syncthreads();
    }
  }

  // C/D layout: col = lane&15, row = (lane>>4)*4 + reg
  if constexpr (MODE == 0) {
    bf16* Qb = (bf16*)(wsp + QOFF);
    bf16* Kb = (bf16*)(wsp + KOFF);
    bf16* Vw = (bf16*)(wsp + VOFF);
#pragma unroll
    for (int nf = 0; nf < 4; ++nf) {
      const int colb = bn * 128 + wc * 64 + nf * 16 + l15; // e in [0,3072)
      const int s = colb >> 10;          // 0:q 1:k 2:v
      const int h = (colb >> 6) & 15;
      const int d = colb & 63;
#pragma unroll
      for (int mf = 0; mf < 4; ++mf) {
#pragma unroll
        for (int rr = 0; rr < 4; ++rr) {
          const int rowg = bm * 128 + wr * 64 + mf * 16 + g * 4 + rr;
          const int bb = rowg >> 11, li = rowg & 2047;
          const float v = acc[mf][nf][rr];
          if (s == 0) {
            Qb[(long)((bb * 16 + h) * 2048 + li) * 64 + d] = (bf16)(v * QSCALE);
          } else if (s == 1) {
            const int sw = (((d >> 3) ^ (li & 7)) << 3) | (d & 7);
            Kb[(long)((bb * 16 + h) * 2048 + li) * 64 + sw] = (bf16)v;
          } else {
            const int lc = li & 63;
            const int sw = (((lc >> 3) ^ (d & 7)) << 3) | (lc & 7);
            Vw[(long)(bb * 16 + h) * 131072 + (li >> 6) * 4096 + d * 64 + sw] = (bf16)v;
          }
        }
      }
    }
  } else {
#pragma unroll
    for (int nf = 0; nf < 4; ++nf) {
      const int colg = bn * 128 + wc * 64 + nf * 16 + l15;
      const float bv = bias[colg];
#pragma unroll
      for (int mf = 0; mf < 4; ++mf) {
#pragma unroll
        for (int rr = 0; rr < 4; ++rr) {
          const int rowg = bm * 128 + wr * 64 + mf * 16 + g * 4 + rr;
          outp[(long)rowg * 1024 + colg] = acc[mf][nf][rr] + bv;
        }
      }
    }
  }
}

// Flash attention, swapped-operand form (round-3 proven). grid 1024, 4 waves.
// Lane owns q = l15; S'[k][q] via mfma(K,Q); P stays in registers for PV.
__global__ __launch_bounds__(256, 4)
void attn_fwd(const bf16* __restrict__ Q, const bf16* __restrict__ Kw,
              const bf16* __restrict__ Vw, bf16* __restrict__ Of)
{
  const int bid  = blockIdx.x;
  const int slot = bid >> 3;
  const int bh   = (bid & 7) * 4 + (slot >> 5);
  const int qt   = slot & 31;
  const int lane = threadIdx.x & 63;
  const int wave = threadIdx.x >> 6;
  const int l15  = lane & 15, g = lane >> 4;

  const bf16* Qh = Q  + (long)bh * 131072;
  const bf16* Ks = Kw + (long)bh * 131072;
  const bf16* Vs = Vw + (long)bh * 131072;

  __shared__ __align__(16) bf16 Klds[2][4096];
  __shared__ __align__(16) bf16 Vlds[2][4096];

  const int q0 = qt * 64 + wave * 16;

  bf16x8 qf[2];
#pragma unroll
  for (int ds = 0; ds < 2; ++ds)
    qf[ds] = *(const bf16x8*)(Qh + (q0 + l15) * 64 + ds * 32 + g * 8);

  auto stage = [&](int t, int buf) {
    const bf16* sk = Ks + t * 4096 + wave * 1024 + lane * 8;
    const bf16* sv = Vs + t * 4096 + wave * 1024 + lane * 8;
    gl16(sk,       &Klds[buf][wave * 1024]);
    gl16(sk + 512, &Klds[buf][wave * 1024 + 512]);
    gl16(sv,       &Vlds[buf][wave * 1024]);
    gl16(sv + 512, &Vlds[buf][wave * 1024 + 512]);
  };

  f32x4 o[4] = {};
  float m = -1e30f, ps = 0.f;

  stage(0, 0);
  __syncthreads();

  for (int t = 0; t < 32; ++t) {
    const int cur = t & 1;
    if (t < 31) stage(t + 1, cur ^ 1);

    // ---- S'[k][q] : A = K-rows (swizzled LDS), B = Q (registers)
    f32x4 sf[4] = {};
#pragma unroll
    for (int kg = 0; kg < 4; ++kg)
#pragma unroll
      for (int ds = 0; ds < 2; ++ds) {
        const bf16x8 kf = *(const bf16x8*)
          &Klds[cur][(kg * 16 + l15) * 64 + (((ds * 4 + g) ^ (l15 & 7)) << 3)];
        sf[kg] = MFMA32(kf, qf[ds], sf[kg]);
      }

    // ---- per-lane softmax for q = l15 (2 shfls), defer-max rescale
    float tm = fmaxf(fmaxf(fmaxf(sf[0][0], sf[0][1]), fmaxf(sf[0][2], sf[0][3])),
                     fmaxf(fmaxf(sf[1][0], sf[1][1]), fmaxf(sf[1][2], sf[1][3])));
    tm = fmaxf(tm, fmaxf(fmaxf(fmaxf(sf[2][0], sf[2][1]), fmaxf(sf[2][2], sf[2][3])),
                         fmaxf(fmaxf(sf[3][0], sf[3][1]), fmaxf(sf[3][2], sf[3][3]))));
    tm = fmaxf(tm, __shfl_xor(tm, 16));
    tm = fmaxf(tm, __shfl_xor(tm, 32));

    if (!__all(tm <= m + 8.f)) {
      const float nm = fmaxf(m, tm);
      const float al = exp2fast(m - nm);
      m = nm;
      ps *= al;
#pragma unroll
      for (int dg = 0; dg < 4; ++dg)
#pragma unroll
        for (int rr = 0; rr < 4; ++rr) o[dg][rr] *= al;
    }

    bf16x4 pa[4];
    float rs0 = 0.f, rs1 = 0.f, rs2 = 0.f, rs3 = 0.f;
#pragma unroll
    for (int kg = 0; kg < 4; ++kg) {
      const float p0 = exp2fast(sf[kg][0] - m);
      const float p1 = exp2fast(sf[kg][1] - m);
      const float p2 = exp2fast(sf[kg][2] - m);
      const float p3 = exp2fast(sf[kg][3] - m);
      rs0 += p0; rs1 += p1; rs2 += p2; rs3 += p3;
      pa[kg][0] = (bf16)p0; pa[kg][1] = (bf16)p1;
      pa[kg][2] = (bf16)p2; pa[kg][3] = (bf16)p3;
    }
    ps += (rs0 + rs1) + (rs2 + rs3);

    // ---- O'[d][q] += V^T-frag * P-frag   (16x16x16, P in-register)
#pragma unroll
    for (int kg = 0; kg < 4; ++kg)
#pragma unroll
      for (int dg = 0; dg < 4; ++dg) {
        const bf16x4 vb = *(const bf16x4*)
          &Vlds[cur][(dg * 16 + l15) * 64 +
                     (((2 * kg + (g >> 1)) ^ (l15 & 7)) << 3) + ((g & 1) << 2)];
        o[dg] = mfma16(vb, pa[kg], o[dg]);
      }
    __syncthreads();   // all reads of buf `cur` done; stages into cur^1 drained
  }

  ps += __shfl_xor(ps, 16);
  ps += __shfl_xor(ps, 32);
  const float inv = 1.f / ps;

  const int b = bh >> 4, h = bh & 15;
#pragma unroll
  for (int dg = 0; dg < 4; ++dg) {
    bf16x4 ov;
#pragma unroll
    for (int rr = 0; rr < 4; ++rr) ov[rr] = (bf16)(o[dg][rr] * inv);
    *(bf16x4*)(Of + (long)(b * 2048 + q0 + l15) * 1024 + h * 64 + dg * 16 + g * 4) = ov;
  }
}

extern "C" void kernel_launch(void* const* d_in, const int* in_sizes, int n_in,
                              void* d_out, int out_size, void* d_ws, size_t ws_size,
                              hipStream_t stream)
{
  (void)in_sizes; (void)n_in; (void)out_size; (void)ws_size;
  const float* x     = (const float*)d_in[0];
  const float* w_qkv = (const float*)d_in[1];
  const float* w_out = (const float*)d_in[2];
  const float* b_out = (const float*)d_in[3];
  float* out = (float*)d_out;
  char*  ws  = (char*)d_ws;

  bf16* Qb  = (bf16*)(ws + QOFF);
  bf16* Kb  = (bf16*)(ws + KOFF);
  bf16* Vw  = (bf16*)(ws + VOFF);
  bf16* xb  = (bf16*)(ws + FOFF);
  bf16* Ofb = (bf16*)(ws + FOFF);   // reuses xb region after gemm0 completes
  bf16* wqb = (bf16*)(ws + WQOFF);
  bf16* wob = (bf16*)(ws + WOOFF);

  cvt_all<<<dim3(4096), 256, 0, stream>>>(x, w_qkv, w_out, xb, wqb, wob);
  gemm_bt<0><<<dim3(24, 32), 256, 0, stream>>>(xb, wqb, nullptr, nullptr, ws);
  attn_fwd<<<dim3(1024), 256, 0, stream>>>(Qb, Kb, Vw, Ofb);
  gemm_bt<1><<<dim3(8, 32), 256, 0, stream>>>(Ofb, wob, out, b_out, ws);
}

// Round 7
// 135.723 us; speedup vs baseline: 2.5021x; 1.0124x over previous
//
#include <hip/hip_runtime.h>

// SelfAttention fused pipeline, MI355X gfx950. bf16 MFMA compute, f32 I/O.
// R7 = green R6 + (a) single-barrier double-buffered GEMM K-loop (T3-minimum
// recipe), (b) max3-shaped max tree in attn softmax. No other changes.
//
//  K0  cvt_all: x, w_qkv, w_out -> bf16 (one dispatch)
//  K1  gemm_bt<0>: qkv = xb @ wqb^T; epilogue scatters Qb (x scale*log2e),
//      Kb/Vw as swizzled 8KB tile images (16B chunk XOR'd by row&7)
//  K2  attn_fwd: flash attn, 4 waves x 16 q-rows, KV tile 64 double-buffered
//      via global_load_lds; online softmax w/ defer-max; P in-register into
//      v_mfma 16x16x16 PV.
//  K3  gemm_bt<1>: out = Of @ wob^T + b_out  (f32 out)
//
// ws: [Qb 8M][Kb 8M][Vw 8M][xb|Of 8M][wqb 6M][wob 2M] = 40 MB

typedef __bf16 bf16;
typedef __bf16 bf16x4 __attribute__((ext_vector_type(4)));
typedef __bf16 bf16x8 __attribute__((ext_vector_type(8)));
typedef float  f32x4 __attribute__((ext_vector_type(4)));

#define MFMA32(A, B, C) __builtin_amdgcn_mfma_f32_16x16x32_bf16((A), (B), (C), 0, 0, 0)

static constexpr long QOFF  = 0;
static constexpr long KOFF  = 8388608;
static constexpr long VOFF  = 16777216;
static constexpr long FOFF  = 25165824;   // xb during gemm0, Of afterwards
static constexpr long WQOFF = 33554432;
static constexpr long WOOFF = 39845888;

// q scale: 1/sqrt(1024) * log2(e)  (softmax in exp2 domain)
#define QSCALE 0.045084222f

__device__ __forceinline__ void gl16(const bf16* g, bf16* l) {
  __builtin_amdgcn_global_load_lds((const __attribute__((address_space(1))) void*)g,
                                   (__attribute__((address_space(3))) void*)l, 16, 0, 0);
}

__device__ __forceinline__ f32x4 mfma16(bf16x4 a, bf16x4 b, f32x4 c) {
  asm("v_mfma_f32_16x16x16_bf16 %0, %1, %2, %0" : "+v"(c) : "v"(a), "v"(b));
  return c;
}

__device__ __forceinline__ float exp2fast(float x) {
#if __has_builtin(__builtin_amdgcn_exp2f)
  return __builtin_amdgcn_exp2f(x);
#else
  return exp2f(x);
#endif
}

__device__ __forceinline__ float max3f(float a, float b, float c) {
  return fmaxf(fmaxf(a, b), c);   // clang fuses to v_max3_f32
}

// one dispatch: 1048576 chunks of 8 f32 -> bf16
__global__ __launch_bounds__(256)
void cvt_all(const float* __restrict__ x, const float* __restrict__ wq,
             const float* __restrict__ wo, bf16* __restrict__ xb,
             bf16* __restrict__ wqb, bf16* __restrict__ wob) {
  const int i = blockIdx.x * 256 + threadIdx.x;
  const float* in; bf16* out; long j;
  if (i < 524288)      { in = x;  out = xb;  j = i; }
  else if (i < 917504) { in = wq; out = wqb; j = i - 524288; }
  else                 { in = wo; out = wob; j = i - 917504; }
  const f32x4 v0 = *(const f32x4*)(in + j * 8);
  const f32x4 v1 = *(const f32x4*)(in + j * 8 + 4);
  bf16x8 o;
#pragma unroll
  for (int k = 0; k < 4; ++k) { o[k] = (bf16)v0[k]; o[k + 4] = (bf16)v1[k]; }
  *(bf16x8*)(out + j * 8) = o;
}

// C[M,N] = A[M,K] * B[N,K]^T, K=1024, bf16 inputs. 128x128 tile, BK=32, 4 waves.
// Single-barrier double-buffer: iter t reads buf t&1, writes buf (t+1)&1, one
// __syncthreads per iter (writes target the non-read buffer; readers drain
// lgkmcnt before the barrier; next epoch's reads follow it).
template <int MODE> // 0: qkv scatter epilogue; 1: f32+bias epilogue
__global__ __launch_bounds__(256, 2)
void gemm_bt(const bf16* __restrict__ Ag, const bf16* __restrict__ Bg,
             float* __restrict__ outp, const float* __restrict__ bias,
             char* __restrict__ wsp)
{
  constexpr int K  = 1024;
  constexpr int NT = K / 32;
  const int bm = blockIdx.y, bn = blockIdx.x;
  const int tid  = threadIdx.x;
  const int lane = tid & 63;
  const int l15  = lane & 15, g = lane >> 4;
  const int wave = tid >> 6;
  const int wr = wave >> 1, wc = wave & 1;

  __shared__ __align__(16) bf16 Ab[2][128 * 40];
  __shared__ __align__(16) bf16 Bb[2][128 * 40];

  const int r  = tid >> 1;
  const int c0 = (tid & 1) * 16;

  const bf16* ap = Ag + (long)(bm * 128 + r) * K + c0;
  const bf16* bp = Bg + (long)(bn * 128 + r) * K + c0;

  bf16x8 a0, a1, b0, b1;
  f32x4 acc[4][4] = {};

  auto load_regs = [&](int t) {
    a0 = *(const bf16x8*)(ap + t * 32);
    a1 = *(const bf16x8*)(ap + t * 32 + 8);
    b0 = *(const bf16x8*)(bp + t * 32);
    b1 = *(const bf16x8*)(bp + t * 32 + 8);
  };
  auto store_lds = [&](int buf) {
    *(bf16x8*)&Ab[buf][r * 40 + c0]     = a0;
    *(bf16x8*)&Ab[buf][r * 40 + c0 + 8] = a1;
    *(bf16x8*)&Bb[buf][r * 40 + c0]     = b0;
    *(bf16x8*)&Bb[buf][r * 40 + c0 + 8] = b1;
  };

  load_regs(0);
  store_lds(0);
  __syncthreads();

#pragma unroll 2
  for (int t = 0; t < NT; ++t) {
    if (t + 1 < NT) load_regs(t + 1);   // global->reg issue for next tile
    const int buf = t & 1;
    bf16x8 af[4], bfv[4];
#pragma unroll
    for (int mf = 0; mf < 4; ++mf)
      af[mf] = *(const bf16x8*)&Ab[buf][(wr * 64 + mf * 16 + l15) * 40 + g * 8];
#pragma unroll
    for (int nf = 0; nf < 4; ++nf)
      bfv[nf] = *(const bf16x8*)&Bb[buf][(wc * 64 + nf * 16 + l15) * 40 + g * 8];
#pragma unroll
    for (int mf = 0; mf < 4; ++mf)
#pragma unroll
      for (int nf = 0; nf < 4; ++nf)
        acc[mf][nf] = MFMA32(af[mf], bfv[nf], acc[mf][nf]);
    if (t + 1 < NT) store_lds((t + 1) & 1);  // write the non-read buffer
    __syncthreads();                         // single barrier per K-step
  }

  // C/D layout: col = lane&15, row = (lane>>4)*4 + reg
  if constexpr (MODE == 0) {
    bf16* Qb = (bf16*)(wsp + QOFF);
    bf16* Kb = (bf16*)(wsp + KOFF);
    bf16* Vw = (bf16*)(wsp + VOFF);
#pragma unroll
    for (int nf = 0; nf < 4; ++nf) {
      const int colb = bn * 128 + wc * 64 + nf * 16 + l15; // e in [0,3072)
      const int s = colb >> 10;          // 0:q 1:k 2:v
      const int h = (colb >> 6) & 15;
      const int d = colb & 63;
#pragma unroll
      for (int mf = 0; mf < 4; ++mf) {
#pragma unroll
        for (int rr = 0; rr < 4; ++rr) {
          const int rowg = bm * 128 + wr * 64 + mf * 16 + g * 4 + rr;
          const int bb = rowg >> 11, li = rowg & 2047;
          const float v = acc[mf][nf][rr];
          if (s == 0) {
            Qb[(long)((bb * 16 + h) * 2048 + li) * 64 + d] = (bf16)(v * QSCALE);
          } else if (s == 1) {
            const int sw = (((d >> 3) ^ (li & 7)) << 3) | (d & 7);
            Kb[(long)((bb * 16 + h) * 2048 + li) * 64 + sw] = (bf16)v;
          } else {
            const int lc = li & 63;
            const int sw = (((lc >> 3) ^ (d & 7)) << 3) | (lc & 7);
            Vw[(long)(bb * 16 + h) * 131072 + (li >> 6) * 4096 + d * 64 + sw] = (bf16)v;
          }
        }
      }
    }
  } else {
#pragma unroll
    for (int nf = 0; nf < 4; ++nf) {
      const int colg = bn * 128 + wc * 64 + nf * 16 + l15;
      const float bv = bias[colg];
#pragma unroll
      for (int mf = 0; mf < 4; ++mf) {
#pragma unroll
        for (int rr = 0; rr < 4; ++rr) {
          const int rowg = bm * 128 + wr * 64 + mf * 16 + g * 4 + rr;
          outp[(long)rowg * 1024 + colg] = acc[mf][nf][rr] + bv;
        }
      }
    }
  }
}

// Flash attention, swapped-operand form. grid 1024 (XCD-swizzled), 4 waves.
// Lane owns q = l15; S'[k][q] via mfma(K,Q); P stays in registers for PV.
__global__ __launch_bounds__(256, 4)
void attn_fwd(const bf16* __restrict__ Q, const bf16* __restrict__ Kw,
              const bf16* __restrict__ Vw, bf16* __restrict__ Of)
{
  const int bid  = blockIdx.x;
  const int slot = bid >> 3;
  const int bh   = (bid & 7) * 4 + (slot >> 5);
  const int qt   = slot & 31;
  const int lane = threadIdx.x & 63;
  const int wave = threadIdx.x >> 6;
  const int l15  = lane & 15, g = lane >> 4;

  const bf16* Qh = Q  + (long)bh * 131072;
  const bf16* Ks = Kw + (long)bh * 131072;
  const bf16* Vs = Vw + (long)bh * 131072;

  __shared__ __align__(16) bf16 Klds[2][4096];
  __shared__ __align__(16) bf16 Vlds[2][4096];

  const int q0 = qt * 64 + wave * 16;

  bf16x8 qf[2];
#pragma unroll
  for (int ds = 0; ds < 2; ++ds)
    qf[ds] = *(const bf16x8*)(Qh + (q0 + l15) * 64 + ds * 32 + g * 8);

  auto stage = [&](int t, int buf) {
    const bf16* sk = Ks + t * 4096 + wave * 1024 + lane * 8;
    const bf16* sv = Vs + t * 4096 + wave * 1024 + lane * 8;
    gl16(sk,       &Klds[buf][wave * 1024]);
    gl16(sk + 512, &Klds[buf][wave * 1024 + 512]);
    gl16(sv,       &Vlds[buf][wave * 1024]);
    gl16(sv + 512, &Vlds[buf][wave * 1024 + 512]);
  };

  f32x4 o[4] = {};
  float m = -1e30f, ps = 0.f;

  stage(0, 0);
  __syncthreads();

  for (int t = 0; t < 32; ++t) {
    const int cur = t & 1;
    if (t < 31) stage(t + 1, cur ^ 1);

    // ---- S'[k][q] : A = K-rows (swizzled LDS), B = Q (registers)
    f32x4 sf[4] = {};
#pragma unroll
    for (int kg = 0; kg < 4; ++kg)
#pragma unroll
      for (int ds = 0; ds < 2; ++ds) {
        const bf16x8 kf = *(const bf16x8*)
          &Klds[cur][(kg * 16 + l15) * 64 + (((ds * 4 + g) ^ (l15 & 7)) << 3)];
        sf[kg] = MFMA32(kf, qf[ds], sf[kg]);
      }

    // ---- per-lane row max (max3 tree: 8 ops), 2 shfls, defer-max rescale
    const float t0 = max3f(sf[0][0], sf[0][1], sf[0][2]);
    const float t1 = max3f(sf[0][3], sf[1][0], sf[1][1]);
    const float t2 = max3f(sf[1][2], sf[1][3], sf[2][0]);
    const float t3 = max3f(sf[2][1], sf[2][2], sf[2][3]);
    const float t4 = max3f(sf[3][0], sf[3][1], sf[3][2]);
    float tm = fmaxf(max3f(t0, t1, t2), max3f(t3, t4, sf[3][3]));
    tm = fmaxf(tm, __shfl_xor(tm, 16));
    tm = fmaxf(tm, __shfl_xor(tm, 32));

    if (!__all(tm <= m + 8.f)) {
      const float nm = fmaxf(m, tm);
      const float al = exp2fast(m - nm);
      m = nm;
      ps *= al;
#pragma unroll
      for (int dg = 0; dg < 4; ++dg)
#pragma unroll
        for (int rr = 0; rr < 4; ++rr) o[dg][rr] *= al;
    }

    bf16x4 pa[4];
    float rs0 = 0.f, rs1 = 0.f, rs2 = 0.f, rs3 = 0.f;
#pragma unroll
    for (int kg = 0; kg < 4; ++kg) {
      const float p0 = exp2fast(sf[kg][0] - m);
      const float p1 = exp2fast(sf[kg][1] - m);
      const float p2 = exp2fast(sf[kg][2] - m);
      const float p3 = exp2fast(sf[kg][3] - m);
      rs0 += p0; rs1 += p1; rs2 += p2; rs3 += p3;
      pa[kg][0] = (bf16)p0; pa[kg][1] = (bf16)p1;
      pa[kg][2] = (bf16)p2; pa[kg][3] = (bf16)p3;
    }
    ps += (rs0 + rs1) + (rs2 + rs3);

    // ---- O'[d][q] += V^T-frag * P-frag   (16x16x16, P in-register)
#pragma unroll
    for (int kg = 0; kg < 4; ++kg)
#pragma unroll
      for (int dg = 0; dg < 4; ++dg) {
        const bf16x4 vb = *(const bf16x4*)
          &Vlds[cur][(dg * 16 + l15) * 64 +
                     (((2 * kg + (g >> 1)) ^ (l15 & 7)) << 3) + ((g & 1) << 2)];
        o[dg] = mfma16(vb, pa[kg], o[dg]);
      }
    __syncthreads();   // all reads of buf `cur` done; stages into cur^1 drained
  }

  ps += __shfl_xor(ps, 16);
  ps += __shfl_xor(ps, 32);
  const float inv = 1.f / ps;

  const int b = bh >> 4, h = bh & 15;
#pragma unroll
  for (int dg = 0; dg < 4; ++dg) {
    bf16x4 ov;
#pragma unroll
    for (int rr = 0; rr < 4; ++rr) ov[rr] = (bf16)(o[dg][rr] * inv);
    *(bf16x4*)(Of + (long)(b * 2048 + q0 + l15) * 1024 + h * 64 + dg * 16 + g * 4) = ov;
  }
}

extern "C" void kernel_launch(void* const* d_in, const int* in_sizes, int n_in,
                              void* d_out, int out_size, void* d_ws, size_t ws_size,
                              hipStream_t stream)
{
  (void)in_sizes; (void)n_in; (void)out_size; (void)ws_size;
  const float* x     = (const float*)d_in[0];
  const float* w_qkv = (const float*)d_in[1];
  const float* w_out = (const float*)d_in[2];
  const float* b_out = (const float*)d_in[3];
  float* out = (float*)d_out;
  char*  ws  = (char*)d_ws;

  bf16* Qb  = (bf16*)(ws + QOFF);
  bf16* Kb  = (bf16*)(ws + KOFF);
  bf16* Vw  = (bf16*)(ws + VOFF);
  bf16* xb  = (bf16*)(ws + FOFF);
  bf16* Ofb = (bf16*)(ws + FOFF);   // reuses xb region after gemm0 completes
  bf16* wqb = (bf16*)(ws + WQOFF);
  bf16* wob = (bf16*)(ws + WOOFF);

  cvt_all<<<dim3(4096), 256, 0, stream>>>(x, w_qkv, w_out, xb, wqb, wob);
  gemm_bt<0><<<dim3(24, 32), 256, 0, stream>>>(xb, wqb, nullptr, nullptr, ws);
  attn_fwd<<<dim3(1024), 256, 0, stream>>>(Qb, Kb, Vw, Ofb);
  gemm_bt<1><<<dim3(8, 32), 256, 0, stream>>>(Ofb, wob, out, b_out, ws);
}

// Round 8
// 135.301 us; speedup vs baseline: 2.5099x; 1.0031x over previous
//
#include <hip/hip_runtime.h>

// SelfAttention fused pipeline, MI355X gfx950. bf16 MFMA compute, f32 I/O.
// R8 = green R7 + attn software pipeline: S-MFMAs computed ONE TILE AHEAD
// (K staged 2-ahead, V 1-ahead), so softmax(t) VALU overlaps S(t+1) matrix
// work. Bit-identical numerics (issue order change only).
//
//  K0  cvt_all: x, w_qkv, w_out -> bf16 (one dispatch)
//  K1  gemm_bt<0>: qkv = xb @ wqb^T; epilogue scatters Qb (x scale*log2e),
//      Kb/Vw as swizzled 8KB tile images (16B chunk XOR'd by row&7)
//  K2  attn_fwd: flash attn, 4 waves x 16 q-rows, KV tile 64; pipelined.
//  K3  gemm_bt<1>: out = Of @ wob^T + b_out  (f32 out)
//
// ws: [Qb 8M][Kb 8M][Vw 8M][xb|Of 8M][wqb 6M][wob 2M] = 40 MB

typedef __bf16 bf16;
typedef __bf16 bf16x4 __attribute__((ext_vector_type(4)));
typedef __bf16 bf16x8 __attribute__((ext_vector_type(8)));
typedef float  f32x4 __attribute__((ext_vector_type(4)));

#define MFMA32(A, B, C) __builtin_amdgcn_mfma_f32_16x16x32_bf16((A), (B), (C), 0, 0, 0)

static constexpr long QOFF  = 0;
static constexpr long KOFF  = 8388608;
static constexpr long VOFF  = 16777216;
static constexpr long FOFF  = 25165824;   // xb during gemm0, Of afterwards
static constexpr long WQOFF = 33554432;
static constexpr long WOOFF = 39845888;

// q scale: 1/sqrt(1024) * log2(e)  (softmax in exp2 domain)
#define QSCALE 0.045084222f

__device__ __forceinline__ void gl16(const bf16* g, bf16* l) {
  __builtin_amdgcn_global_load_lds((const __attribute__((address_space(1))) void*)g,
                                   (__attribute__((address_space(3))) void*)l, 16, 0, 0);
}

__device__ __forceinline__ f32x4 mfma16(bf16x4 a, bf16x4 b, f32x4 c) {
  asm("v_mfma_f32_16x16x16_bf16 %0, %1, %2, %0" : "+v"(c) : "v"(a), "v"(b));
  return c;
}

__device__ __forceinline__ float exp2fast(float x) {
#if __has_builtin(__builtin_amdgcn_exp2f)
  return __builtin_amdgcn_exp2f(x);
#else
  return exp2f(x);
#endif
}

__device__ __forceinline__ float max3f(float a, float b, float c) {
  return fmaxf(fmaxf(a, b), c);   // clang fuses to v_max3_f32
}

// one dispatch: 1048576 chunks of 8 f32 -> bf16
__global__ __launch_bounds__(256)
void cvt_all(const float* __restrict__ x, const float* __restrict__ wq,
             const float* __restrict__ wo, bf16* __restrict__ xb,
             bf16* __restrict__ wqb, bf16* __restrict__ wob) {
  const int i = blockIdx.x * 256 + threadIdx.x;
  const float* in; bf16* out; long j;
  if (i < 524288)      { in = x;  out = xb;  j = i; }
  else if (i < 917504) { in = wq; out = wqb; j = i - 524288; }
  else                 { in = wo; out = wob; j = i - 917504; }
  const f32x4 v0 = *(const f32x4*)(in + j * 8);
  const f32x4 v1 = *(const f32x4*)(in + j * 8 + 4);
  bf16x8 o;
#pragma unroll
  for (int k = 0; k < 4; ++k) { o[k] = (bf16)v0[k]; o[k + 4] = (bf16)v1[k]; }
  *(bf16x8*)(out + j * 8) = o;
}

// C[M,N] = A[M,K] * B[N,K]^T, K=1024, bf16 inputs. 128x128 tile, BK=32, 4 waves.
// Single-barrier double-buffer (green R7).
template <int MODE> // 0: qkv scatter epilogue; 1: f32+bias epilogue
__global__ __launch_bounds__(256, 2)
void gemm_bt(const bf16* __restrict__ Ag, const bf16* __restrict__ Bg,
             float* __restrict__ outp, const float* __restrict__ bias,
             char* __restrict__ wsp)
{
  constexpr int K  = 1024;
  constexpr int NT = K / 32;
  const int bm = blockIdx.y, bn = blockIdx.x;
  const int tid  = threadIdx.x;
  const int lane = tid & 63;
  const int l15  = lane & 15, g = lane >> 4;
  const int wave = tid >> 6;
  const int wr = wave >> 1, wc = wave & 1;

  __shared__ __align__(16) bf16 Ab[2][128 * 40];
  __shared__ __align__(16) bf16 Bb[2][128 * 40];

  const int r  = tid >> 1;
  const int c0 = (tid & 1) * 16;

  const bf16* ap = Ag + (long)(bm * 128 + r) * K + c0;
  const bf16* bp = Bg + (long)(bn * 128 + r) * K + c0;

  bf16x8 a0, a1, b0, b1;
  f32x4 acc[4][4] = {};

  auto load_regs = [&](int t) {
    a0 = *(const bf16x8*)(ap + t * 32);
    a1 = *(const bf16x8*)(ap + t * 32 + 8);
    b0 = *(const bf16x8*)(bp + t * 32);
    b1 = *(const bf16x8*)(bp + t * 32 + 8);
  };
  auto store_lds = [&](int buf) {
    *(bf16x8*)&Ab[buf][r * 40 + c0]     = a0;
    *(bf16x8*)&Ab[buf][r * 40 + c0 + 8] = a1;
    *(bf16x8*)&Bb[buf][r * 40 + c0]     = b0;
    *(bf16x8*)&Bb[buf][r * 40 + c0 + 8] = b1;
  };

  load_regs(0);
  store_lds(0);
  __syncthreads();

#pragma unroll 2
  for (int t = 0; t < NT; ++t) {
    if (t + 1 < NT) load_regs(t + 1);   // global->reg issue for next tile
    const int buf = t & 1;
    bf16x8 af[4], bfv[4];
#pragma unroll
    for (int mf = 0; mf < 4; ++mf)
      af[mf] = *(const bf16x8*)&Ab[buf][(wr * 64 + mf * 16 + l15) * 40 + g * 8];
#pragma unroll
    for (int nf = 0; nf < 4; ++nf)
      bfv[nf] = *(const bf16x8*)&Bb[buf][(wc * 64 + nf * 16 + l15) * 40 + g * 8];
#pragma unroll
    for (int mf = 0; mf < 4; ++mf)
#pragma unroll
      for (int nf = 0; nf < 4; ++nf)
        acc[mf][nf] = MFMA32(af[mf], bfv[nf], acc[mf][nf]);
    if (t + 1 < NT) store_lds((t + 1) & 1);  // write the non-read buffer
    __syncthreads();                         // single barrier per K-step
  }

  // C/D layout: col = lane&15, row = (lane>>4)*4 + reg
  if constexpr (MODE == 0) {
    bf16* Qb = (bf16*)(wsp + QOFF);
    bf16* Kb = (bf16*)(wsp + KOFF);
    bf16* Vw = (bf16*)(wsp + VOFF);
#pragma unroll
    for (int nf = 0; nf < 4; ++nf) {
      const int colb = bn * 128 + wc * 64 + nf * 16 + l15; // e in [0,3072)
      const int s = colb >> 10;          // 0:q 1:k 2:v
      const int h = (colb >> 6) & 15;
      const int d = colb & 63;
#pragma unroll
      for (int mf = 0; mf < 4; ++mf) {
#pragma unroll
        for (int rr = 0; rr < 4; ++rr) {
          const int rowg = bm * 128 + wr * 64 + mf * 16 + g * 4 + rr;
          const int bb = rowg >> 11, li = rowg & 2047;
          const float v = acc[mf][nf][rr];
          if (s == 0) {
            Qb[(long)((bb * 16 + h) * 2048 + li) * 64 + d] = (bf16)(v * QSCALE);
          } else if (s == 1) {
            const int sw = (((d >> 3) ^ (li & 7)) << 3) | (d & 7);
            Kb[(long)((bb * 16 + h) * 2048 + li) * 64 + sw] = (bf16)v;
          } else {
            const int lc = li & 63;
            const int sw = (((lc >> 3) ^ (d & 7)) << 3) | (lc & 7);
            Vw[(long)(bb * 16 + h) * 131072 + (li >> 6) * 4096 + d * 64 + sw] = (bf16)v;
          }
        }
      }
    }
  } else {
#pragma unroll
    for (int nf = 0; nf < 4; ++nf) {
      const int colg = bn * 128 + wc * 64 + nf * 16 + l15;
      const float bv = bias[colg];
#pragma unroll
      for (int mf = 0; mf < 4; ++mf) {
#pragma unroll
        for (int rr = 0; rr < 4; ++rr) {
          const int rowg = bm * 128 + wr * 64 + mf * 16 + g * 4 + rr;
          outp[(long)rowg * 1024 + colg] = acc[mf][nf][rr] + bv;
        }
      }
    }
  }
}

// Flash attention, swapped-operand, pipelined: S(t+1) MFMAs issued before
// softmax(t) so VALU and matrix pipes overlap. K staged 2-ahead, V 1-ahead;
// buffer parity: at body t, read K[(t+1)&1] and V[t&1]; write K[t&1] (=K(t+2))
// and V[(t+1)&1] (=V(t+1)) -- writers never touch a buffer with in-flight
// reads (previous readers drained at the end-of-(t-1) barrier).
__global__ __launch_bounds__(256, 4)
void attn_fwd(const bf16* __restrict__ Q, const bf16* __restrict__ Kw,
              const bf16* __restrict__ Vw, bf16* __restrict__ Of)
{
  const int bid  = blockIdx.x;
  const int slot = bid >> 3;
  const int bh   = (bid & 7) * 4 + (slot >> 5);
  const int qt   = slot & 31;
  const int lane = threadIdx.x & 63;
  const int wave = threadIdx.x >> 6;
  const int l15  = lane & 15, g = lane >> 4;

  const bf16* Qh = Q  + (long)bh * 131072;
  const bf16* Ks = Kw + (long)bh * 131072;
  const bf16* Vs = Vw + (long)bh * 131072;

  __shared__ __align__(16) bf16 Klds[2][4096];
  __shared__ __align__(16) bf16 Vlds[2][4096];

  const int q0 = qt * 64 + wave * 16;

  bf16x8 qf[2];
#pragma unroll
  for (int ds = 0; ds < 2; ++ds)
    qf[ds] = *(const bf16x8*)(Qh + (q0 + l15) * 64 + ds * 32 + g * 8);

  auto stageK = [&](int t, int buf) {
    const bf16* sk = Ks + t * 4096 + wave * 1024 + lane * 8;
    gl16(sk,       &Klds[buf][wave * 1024]);
    gl16(sk + 512, &Klds[buf][wave * 1024 + 512]);
  };
  auto stageV = [&](int t, int buf) {
    const bf16* sv = Vs + t * 4096 + wave * 1024 + lane * 8;
    gl16(sv,       &Vlds[buf][wave * 1024]);
    gl16(sv + 512, &Vlds[buf][wave * 1024 + 512]);
  };

  f32x4 o[4] = {};
  float m = -1e30f, ps = 0.f;
  f32x4 sfA[4], sfB[4];

#define COMPUTE_S(BUF, SF) do {                                               \
  _Pragma("unroll")                                                           \
  for (int kg = 0; kg < 4; ++kg) {                                            \
    SF[kg] = f32x4{0.f, 0.f, 0.f, 0.f};                                       \
    _Pragma("unroll")                                                         \
    for (int ds = 0; ds < 2; ++ds) {                                          \
      const bf16x8 kf = *(const bf16x8*)                                      \
        &Klds[BUF][(kg * 16 + l15) * 64 + (((ds * 4 + g) ^ (l15 & 7)) << 3)]; \
      SF[kg] = MFMA32(kf, qf[ds], SF[kg]);                                    \
    }                                                                         \
  }                                                                           \
} while (0)

#define ATTN_BODY(T, SFC, SFN) do {                                           \
  if ((T) <= 29) stageK((T) + 2, (T) & 1);                                    \
  if ((T) <= 30) stageV((T) + 1, ((T) + 1) & 1);                              \
  if ((T) <= 30) COMPUTE_S(((T) + 1) & 1, SFN);                               \
  const float t0 = max3f(SFC[0][0], SFC[0][1], SFC[0][2]);                    \
  const float t1 = max3f(SFC[0][3], SFC[1][0], SFC[1][1]);                    \
  const float t2 = max3f(SFC[1][2], SFC[1][3], SFC[2][0]);                    \
  const float t3 = max3f(SFC[2][1], SFC[2][2], SFC[2][3]);                    \
  const float t4 = max3f(SFC[3][0], SFC[3][1], SFC[3][2]);                    \
  float tm = fmaxf(max3f(t0, t1, t2), max3f(t3, t4, SFC[3][3]));              \
  tm = fmaxf(tm, __shfl_xor(tm, 16));                                         \
  tm = fmaxf(tm, __shfl_xor(tm, 32));                                         \
  if (!__all(tm <= m + 8.f)) {                                                \
    const float nm = fmaxf(m, tm);                                            \
    const float al = exp2fast(m - nm);                                        \
    m = nm;                                                                   \
    ps *= al;                                                                 \
    _Pragma("unroll")                                                         \
    for (int dg = 0; dg < 4; ++dg)                                            \
      _Pragma("unroll")                                                       \
      for (int rr = 0; rr < 4; ++rr) o[dg][rr] *= al;                         \
  }                                                                           \
  bf16x4 pa[4];                                                               \
  float rs0 = 0.f, rs1 = 0.f, rs2 = 0.f, rs3 = 0.f;                           \
  _Pragma("unroll")                                                           \
  for (int kg = 0; kg < 4; ++kg) {                                            \
    const float p0 = exp2fast(SFC[kg][0] - m);                                \
    const float p1 = exp2fast(SFC[kg][1] - m);                                \
    const float p2 = exp2fast(SFC[kg][2] - m);                                \
    const float p3 = exp2fast(SFC[kg][3] - m);                                \
    rs0 += p0; rs1 += p1; rs2 += p2; rs3 += p3;                               \
    pa[kg][0] = (bf16)p0; pa[kg][1] = (bf16)p1;                               \
    pa[kg][2] = (bf16)p2; pa[kg][3] = (bf16)p3;                               \
  }                                                                           \
  ps += (rs0 + rs1) + (rs2 + rs3);                                            \
  _Pragma("unroll")                                                           \
  for (int kg = 0; kg < 4; ++kg)                                              \
    _Pragma("unroll")                                                         \
    for (int dg = 0; dg < 4; ++dg) {                                          \
      const bf16x4 vb = *(const bf16x4*)                                      \
        &Vlds[(T) & 1][(dg * 16 + l15) * 64 +                                 \
                       (((2 * kg + (g >> 1)) ^ (l15 & 7)) << 3) +             \
                       ((g & 1) << 2)];                                       \
      o[dg] = mfma16(vb, pa[kg], o[dg]);                                      \
    }                                                                         \
  __syncthreads();                                                            \
} while (0)

  // prologue: K0,V0 staged+drained; S(0) computed; K1 staged+drained
  stageK(0, 0);
  stageV(0, 0);
  __syncthreads();
  stageK(1, 1);
  COMPUTE_S(0, sfA);
  __syncthreads();

#pragma unroll 1
  for (int tp = 0; tp < 32; tp += 2) {
    ATTN_BODY(tp, sfA, sfB);
    ATTN_BODY(tp + 1, sfB, sfA);
  }

#undef ATTN_BODY
#undef COMPUTE_S

  ps += __shfl_xor(ps, 16);
  ps += __shfl_xor(ps, 32);
  const float inv = 1.f / ps;

  const int b = bh >> 4, h = bh & 15;
#pragma unroll
  for (int dg = 0; dg < 4; ++dg) {
    bf16x4 ov;
#pragma unroll
    for (int rr = 0; rr < 4; ++rr) ov[rr] = (bf16)(o[dg][rr] * inv);
    *(bf16x4*)(Of + (long)(b * 2048 + q0 + l15) * 1024 + h * 64 + dg * 16 + g * 4) = ov;
  }
}

extern "C" void kernel_launch(void* const* d_in, const int* in_sizes, int n_in,
                              void* d_out, int out_size, void* d_ws, size_t ws_size,
                              hipStream_t stream)
{
  (void)in_sizes; (void)n_in; (void)out_size; (void)ws_size;
  const float* x     = (const float*)d_in[0];
  const float* w_qkv = (const float*)d_in[1];
  const float* w_out = (const float*)d_in[2];
  const float* b_out = (const float*)d_in[3];
  float* out = (float*)d_out;
  char*  ws  = (char*)d_ws;

  bf16* Qb  = (bf16*)(ws + QOFF);
  bf16* Kb  = (bf16*)(ws + KOFF);
  bf16* Vw  = (bf16*)(ws + VOFF);
  bf16* xb  = (bf16*)(ws + FOFF);
  bf16* Ofb = (bf16*)(ws + FOFF);   // reuses xb region after gemm0 completes
  bf16* wqb = (bf16*)(ws + WQOFF);
  bf16* wob = (bf16*)(ws + WOOFF);

  cvt_all<<<dim3(4096), 256, 0, stream>>>(x, w_qkv, w_out, xb, wqb, wob);
  gemm_bt<0><<<dim3(24, 32), 256, 0, stream>>>(xb, wqb, nullptr, nullptr, ws);
  attn_fwd<<<dim3(1024), 256, 0, stream>>>(Qb, Kb, Vw, Ofb);
  gemm_bt<1><<<dim3(8, 32), 256, 0, stream>>>(Ofb, wob, out, b_out, ws);
}

// Round 10
// 135.167 us; speedup vs baseline: 2.5124x; 1.0010x over previous
//
#include <hip/hip_runtime.h>

// SelfAttention fused pipeline, MI355X gfx950. bf16 MFMA compute, f32 I/O.
// R10 = green R8 + ONE delta: gemm_bt __launch_bounds__(256,3) (3 blocks/CU).
// Attn keeps ONLINE defer-max softmax permanently: R9 convicted fixed-shift
// (exp2 of rare garbage S -> inf -> NaN); online exp2(S-m) clamps P<=2^8 and
// is the proven-green guard (R3/R6/R7/R8).
//
//  K0  cvt_all: x, w_qkv, w_out -> bf16 (one dispatch)
//  K1  gemm_bt<0>: qkv = xb @ wqb^T; epilogue scatters Qb (x scale*log2e),
//      Kb/Vw as swizzled 8KB tile images (16B chunk XOR'd by row&7)
//  K2  attn_fwd: flash attn, 4 waves x 16 q-rows, KV tile 64; S pipelined
//      one tile ahead; online defer-max softmax; P in-register PV (16x16x16).
//  K3  gemm_bt<1>: out = Of @ wob^T + b_out  (f32 out)
//
// ws: [Qb 8M][Kb 8M][Vw 8M][xb|Of 8M][wqb 6M][wob 2M] = 40 MB

typedef __bf16 bf16;
typedef __bf16 bf16x4 __attribute__((ext_vector_type(4)));
typedef __bf16 bf16x8 __attribute__((ext_vector_type(8)));
typedef float  f32x4 __attribute__((ext_vector_type(4)));

#define MFMA32(A, B, C) __builtin_amdgcn_mfma_f32_16x16x32_bf16((A), (B), (C), 0, 0, 0)

static constexpr long QOFF  = 0;
static constexpr long KOFF  = 8388608;
static constexpr long VOFF  = 16777216;
static constexpr long FOFF  = 25165824;   // xb during gemm0, Of afterwards
static constexpr long WQOFF = 33554432;
static constexpr long WOOFF = 39845888;

// q scale: 1/sqrt(1024) * log2(e)  (softmax in exp2 domain)
#define QSCALE 0.045084222f

__device__ __forceinline__ void gl16(const bf16* g, bf16* l) {
  __builtin_amdgcn_global_load_lds((const __attribute__((address_space(1))) void*)g,
                                   (__attribute__((address_space(3))) void*)l, 16, 0, 0);
}

__device__ __forceinline__ f32x4 mfma16(bf16x4 a, bf16x4 b, f32x4 c) {
  asm("v_mfma_f32_16x16x16_bf16 %0, %1, %2, %0" : "+v"(c) : "v"(a), "v"(b));
  return c;
}

__device__ __forceinline__ float exp2fast(float x) {
#if __has_builtin(__builtin_amdgcn_exp2f)
  return __builtin_amdgcn_exp2f(x);
#else
  return exp2f(x);
#endif
}

__device__ __forceinline__ float max3f(float a, float b, float c) {
  return fmaxf(fmaxf(a, b), c);   // clang fuses to v_max3_f32
}

// one dispatch: 1048576 chunks of 8 f32 -> bf16
__global__ __launch_bounds__(256)
void cvt_all(const float* __restrict__ x, const float* __restrict__ wq,
             const float* __restrict__ wo, bf16* __restrict__ xb,
             bf16* __restrict__ wqb, bf16* __restrict__ wob) {
  const int i = blockIdx.x * 256 + threadIdx.x;
  const float* in; bf16* out; long j;
  if (i < 524288)      { in = x;  out = xb;  j = i; }
  else if (i < 917504) { in = wq; out = wqb; j = i - 524288; }
  else                 { in = wo; out = wob; j = i - 917504; }
  const f32x4 v0 = *(const f32x4*)(in + j * 8);
  const f32x4 v1 = *(const f32x4*)(in + j * 8 + 4);
  bf16x8 o;
#pragma unroll
  for (int k = 0; k < 4; ++k) { o[k] = (bf16)v0[k]; o[k + 4] = (bf16)v1[k]; }
  *(bf16x8*)(out + j * 8) = o;
}

// C[M,N] = A[M,K] * B[N,K]^T, K=1024, bf16 inputs. 128x128 tile, BK=32, 4 waves.
// Single-barrier double-buffer; 3 blocks/CU (VGPR cap 170, LDS 3x40KB=120KB).
template <int MODE> // 0: qkv scatter epilogue; 1: f32+bias epilogue
__global__ __launch_bounds__(256, 3)
void gemm_bt(const bf16* __restrict__ Ag, const bf16* __restrict__ Bg,
             float* __restrict__ outp, const float* __restrict__ bias,
             char* __restrict__ wsp)
{
  constexpr int K  = 1024;
  constexpr int NT = K / 32;
  const int bm = blockIdx.y, bn = blockIdx.x;
  const int tid  = threadIdx.x;
  const int lane = tid & 63;
  const int l15  = lane & 15, g = lane >> 4;
  const int wave = tid >> 6;
  const int wr = wave >> 1, wc = wave & 1;

  __shared__ __align__(16) bf16 Ab[2][128 * 40];
  __shared__ __align__(16) bf16 Bb[2][128 * 40];

  const int r  = tid >> 1;
  const int c0 = (tid & 1) * 16;

  const bf16* ap = Ag + (long)(bm * 128 + r) * K + c0;
  const bf16* bp = Bg + (long)(bn * 128 + r) * K + c0;

  bf16x8 a0, a1, b0, b1;
  f32x4 acc[4][4] = {};

  auto load_regs = [&](int t) {
    a0 = *(const bf16x8*)(ap + t * 32);
    a1 = *(const bf16x8*)(ap + t * 32 + 8);
    b0 = *(const bf16x8*)(bp + t * 32);
    b1 = *(const bf16x8*)(bp + t * 32 + 8);
  };
  auto store_lds = [&](int buf) {
    *(bf16x8*)&Ab[buf][r * 40 + c0]     = a0;
    *(bf16x8*)&Ab[buf][r * 40 + c0 + 8] = a1;
    *(bf16x8*)&Bb[buf][r * 40 + c0]     = b0;
    *(bf16x8*)&Bb[buf][r * 40 + c0 + 8] = b1;
  };

  load_regs(0);
  store_lds(0);
  __syncthreads();

#pragma unroll 2
  for (int t = 0; t < NT; ++t) {
    if (t + 1 < NT) load_regs(t + 1);   // global->reg issue for next tile
    const int buf = t & 1;
    bf16x8 af[4], bfv[4];
#pragma unroll
    for (int mf = 0; mf < 4; ++mf)
      af[mf] = *(const bf16x8*)&Ab[buf][(wr * 64 + mf * 16 + l15) * 40 + g * 8];
#pragma unroll
    for (int nf = 0; nf < 4; ++nf)
      bfv[nf] = *(const bf16x8*)&Bb[buf][(wc * 64 + nf * 16 + l15) * 40 + g * 8];
#pragma unroll
    for (int mf = 0; mf < 4; ++mf)
#pragma unroll
      for (int nf = 0; nf < 4; ++nf)
        acc[mf][nf] = MFMA32(af[mf], bfv[nf], acc[mf][nf]);
    if (t + 1 < NT) store_lds((t + 1) & 1);  // write the non-read buffer
    __syncthreads();                         // single barrier per K-step
  }

  // C/D layout: col = lane&15, row = (lane>>4)*4 + reg
  if constexpr (MODE == 0) {
    bf16* Qb = (bf16*)(wsp + QOFF);
    bf16* Kb = (bf16*)(wsp + KOFF);
    bf16* Vw = (bf16*)(wsp + VOFF);
#pragma unroll
    for (int nf = 0; nf < 4; ++nf) {
      const int colb = bn * 128 + wc * 64 + nf * 16 + l15; // e in [0,3072)
      const int s = colb >> 10;          // 0:q 1:k 2:v
      const int h = (colb >> 6) & 15;
      const int d = colb & 63;
#pragma unroll
      for (int mf = 0; mf < 4; ++mf) {
#pragma unroll
        for (int rr = 0; rr < 4; ++rr) {
          const int rowg = bm * 128 + wr * 64 + mf * 16 + g * 4 + rr;
          const int bb = rowg >> 11, li = rowg & 2047;
          const float v = acc[mf][nf][rr];
          if (s == 0) {
            Qb[(long)((bb * 16 + h) * 2048 + li) * 64 + d] = (bf16)(v * QSCALE);
          } else if (s == 1) {
            const int sw = (((d >> 3) ^ (li & 7)) << 3) | (d & 7);
            Kb[(long)((bb * 16 + h) * 2048 + li) * 64 + sw] = (bf16)v;
          } else {
            const int lc = li & 63;
            const int sw = (((lc >> 3) ^ (d & 7)) << 3) | (lc & 7);
            Vw[(long)(bb * 16 + h) * 131072 + (li >> 6) * 4096 + d * 64 + sw] = (bf16)v;
          }
        }
      }
    }
  } else {
#pragma unroll
    for (int nf = 0; nf < 4; ++nf) {
      const int colg = bn * 128 + wc * 64 + nf * 16 + l15;
      const float bv = bias[colg];
#pragma unroll
      for (int mf = 0; mf < 4; ++mf) {
#pragma unroll
        for (int rr = 0; rr < 4; ++rr) {
          const int rowg = bm * 128 + wr * 64 + mf * 16 + g * 4 + rr;
          outp[(long)rowg * 1024 + colg] = acc[mf][nf][rr] + bv;
        }
      }
    }
  }
}

// Flash attention, swapped-operand, pipelined: S(t+1) MFMAs issued before
// softmax(t). K staged 2-ahead, V 1-ahead. Online defer-max softmax (guard).
__global__ __launch_bounds__(256, 4)
void attn_fwd(const bf16* __restrict__ Q, const bf16* __restrict__ Kw,
              const bf16* __restrict__ Vw, bf16* __restrict__ Of)
{
  const int bid  = blockIdx.x;
  const int slot = bid >> 3;
  const int bh   = (bid & 7) * 4 + (slot >> 5);
  const int qt   = slot & 31;
  const int lane = threadIdx.x & 63;
  const int wave = threadIdx.x >> 6;
  const int l15  = lane & 15, g = lane >> 4;

  const bf16* Qh = Q  + (long)bh * 131072;
  const bf16* Ks = Kw + (long)bh * 131072;
  const bf16* Vs = Vw + (long)bh * 131072;

  __shared__ __align__(16) bf16 Klds[2][4096];
  __shared__ __align__(16) bf16 Vlds[2][4096];

  const int q0 = qt * 64 + wave * 16;

  bf16x8 qf[2];
#pragma unroll
  for (int ds = 0; ds < 2; ++ds)
    qf[ds] = *(const bf16x8*)(Qh + (q0 + l15) * 64 + ds * 32 + g * 8);

  auto stageK = [&](int t, int buf) {
    const bf16* sk = Ks + t * 4096 + wave * 1024 + lane * 8;
    gl16(sk,       &Klds[buf][wave * 1024]);
    gl16(sk + 512, &Klds[buf][wave * 1024 + 512]);
  };
  auto stageV = [&](int t, int buf) {
    const bf16* sv = Vs + t * 4096 + wave * 1024 + lane * 8;
    gl16(sv,       &Vlds[buf][wave * 1024]);
    gl16(sv + 512, &Vlds[buf][wave * 1024 + 512]);
  };

  f32x4 o[4] = {};
  float m = -1e30f, ps = 0.f;
  f32x4 sfA[4], sfB[4];

#define COMPUTE_S(BUF, SF) do {                                               \
  _Pragma("unroll")                                                           \
  for (int kg = 0; kg < 4; ++kg) {                                            \
    SF[kg] = f32x4{0.f, 0.f, 0.f, 0.f};                                       \
    _Pragma("unroll")                                                         \
    for (int ds = 0; ds < 2; ++ds) {                                          \
      const bf16x8 kf = *(const bf16x8*)                                      \
        &Klds[BUF][(kg * 16 + l15) * 64 + (((ds * 4 + g) ^ (l15 & 7)) << 3)]; \
      SF[kg] = MFMA32(kf, qf[ds], SF[kg]);                                    \
    }                                                                         \
  }                                                                           \
} while (0)

#define ATTN_BODY(T, SFC, SFN) do {                                           \
  if ((T) <= 29) stageK((T) + 2, (T) & 1);                                    \
  if ((T) <= 30) stageV((T) + 1, ((T) + 1) & 1);                              \
  if ((T) <= 30) COMPUTE_S(((T) + 1) & 1, SFN);                               \
  const float t0 = max3f(SFC[0][0], SFC[0][1], SFC[0][2]);                    \
  const float t1 = max3f(SFC[0][3], SFC[1][0], SFC[1][1]);                    \
  const float t2 = max3f(SFC[1][2], SFC[1][3], SFC[2][0]);                    \
  const float t3 = max3f(SFC[2][1], SFC[2][2], SFC[2][3]);                    \
  const float t4 = max3f(SFC[3][0], SFC[3][1], SFC[3][2]);                    \
  float tm = fmaxf(max3f(t0, t1, t2), max3f(t3, t4, SFC[3][3]));              \
  tm = fmaxf(tm, __shfl_xor(tm, 16));                                         \
  tm = fmaxf(tm, __shfl_xor(tm, 32));                                         \
  if (!__all(tm <= m + 8.f)) {                                                \
    const float nm = fmaxf(m, tm);                                            \
    const float al = exp2fast(m - nm);                                        \
    m = nm;                                                                   \
    ps *= al;                                                                 \
    _Pragma("unroll")                                                         \
    for (int dg = 0; dg < 4; ++dg)                                            \
      _Pragma("unroll")                                                       \
      for (int rr = 0; rr < 4; ++rr) o[dg][rr] *= al;                         \
  }                                                                           \
  bf16x4 pa[4];                                                               \
  float rs0 = 0.f, rs1 = 0.f, rs2 = 0.f, rs3 = 0.f;                           \
  _Pragma("unroll")                                                           \
  for (int kg = 0; kg < 4; ++kg) {                                            \
    const float p0 = exp2fast(SFC[kg][0] - m);                                \
    const float p1 = exp2fast(SFC[kg][1] - m);                                \
    const float p2 = exp2fast(SFC[kg][2] - m);                                \
    const float p3 = exp2fast(SFC[kg][3] - m);                                \
    rs0 += p0; rs1 += p1; rs2 += p2; rs3 += p3;                               \
    pa[kg][0] = (bf16)p0; pa[kg][1] = (bf16)p1;                               \
    pa[kg][2] = (bf16)p2; pa[kg][3] = (bf16)p3;                               \
  }                                                                           \
  ps += (rs0 + rs1) + (rs2 + rs3);                                            \
  _Pragma("unroll")                                                           \
  for (int kg = 0; kg < 4; ++kg)                                              \
    _Pragma("unroll")                                                         \
    for (int dg = 0; dg < 4; ++dg) {                                          \
      const bf16x4 vb = *(const bf16x4*)                                      \
        &Vlds[(T) & 1][(dg * 16 + l15) * 64 +                                 \
                       (((2 * kg + (g >> 1)) ^ (l15 & 7)) << 3) +             \
                       ((g & 1) << 2)];                                       \
      o[dg] = mfma16(vb, pa[kg], o[dg]);                                      \
    }                                                                         \
  __syncthreads();                                                            \
} while (0)

  // prologue: K0,V0 staged+drained; S(0) computed; K1 staged+drained
  stageK(0, 0);
  stageV(0, 0);
  __syncthreads();
  stageK(1, 1);
  COMPUTE_S(0, sfA);
  __syncthreads();

#pragma unroll 1
  for (int tp = 0; tp < 32; tp += 2) {
    ATTN_BODY(tp, sfA, sfB);
    ATTN_BODY(tp + 1, sfB, sfA);
  }

#undef ATTN_BODY
#undef COMPUTE_S

  ps += __shfl_xor(ps, 16);
  ps += __shfl_xor(ps, 32);
  const float inv = 1.f / ps;

  const int b = bh >> 4, h = bh & 15;
#pragma unroll
  for (int dg = 0; dg < 4; ++dg) {
    bf16x4 ov;
#pragma unroll
    for (int rr = 0; rr < 4; ++rr) ov[rr] = (bf16)(o[dg][rr] * inv);
    *(bf16x4*)(Of + (long)(b * 2048 + q0 + l15) * 1024 + h * 64 + dg * 16 + g * 4) = ov;
  }
}

extern "C" void kernel_launch(void* const* d_in, const int* in_sizes, int n_in,
                              void* d_out, int out_size, void* d_ws, size_t ws_size,
                              hipStream_t stream)
{
  (void)in_sizes; (void)n_in; (void)out_size; (void)ws_size;
  const float* x     = (const float*)d_in[0];
  const float* w_qkv = (const float*)d_in[1];
  const float* w_out = (const float*)d_in[2];
  const float* b_out = (const float*)d_in[3];
  float* out = (float*)d_out;
  char*  ws  = (char*)d_ws;

  bf16* Qb  = (bf16*)(ws + QOFF);
  bf16* Kb  = (bf16*)(ws + KOFF);
  bf16* Vw  = (bf16*)(ws + VOFF);
  bf16* xb  = (bf16*)(ws + FOFF);
  bf16* Ofb = (bf16*)(ws + FOFF);   // reuses xb region after gemm0 completes
  bf16* wqb = (bf16*)(ws + WQOFF);
  bf16* wob = (bf16*)(ws + WOOFF);

  cvt_all<<<dim3(4096), 256, 0, stream>>>(x, w_qkv, w_out, xb, wqb, wob);
  gemm_bt<0><<<dim3(24, 32), 256, 0, stream>>>(xb, wqb, nullptr, nullptr, ws);
  attn_fwd<<<dim3(1024), 256, 0, stream>>>(Qb, Kb, Vw, Ofb);
  gemm_bt<1><<<dim3(8, 32), 256, 0, stream>>>(Ofb, wob, out, b_out, ws);
}

// Round 12
// 135.123 us; speedup vs baseline: 2.5132x; 1.0003x over previous
//
#include <hip/hip_runtime.h>

// SelfAttention fused pipeline, MI355X gfx950. bf16 MFMA compute, f32 I/O.
// R12 = exact green R10 + T5 s_setprio(1) around attn MFMA clusters (S and PV).
// Pure scheduler hint: no semantic change; R10 greenness carries over.
// Attn restructures (128-row blocks) are CLOSED: R4/R5/R11 all failed there
// with no identifiable defect after 4 audits — model hole, stop gambling.
//
//  K0  cvt_all: x, w_qkv, w_out -> bf16 (one dispatch)
//  K1  gemm_bt<0>: qkv = xb @ wqb^T; epilogue scatters Qb (x scale*log2e),
//      Kb/Vw as swizzled 8KB tile images (16B chunk XOR'd by row&7)
//  K2  attn_fwd: flash attn, 4 waves x 16 q-rows, KV tile 64; S pipelined
//      one tile ahead; online defer-max softmax; P in-register PV (16x16x16).
//  K3  gemm_bt<1>: out = Of @ wob^T + b_out  (f32 out)
//
// ws: [Qb 8M][Kb 8M][Vw 8M][xb|Of 8M][wqb 6M][wob 2M] = 40 MB

typedef __bf16 bf16;
typedef __bf16 bf16x4 __attribute__((ext_vector_type(4)));
typedef __bf16 bf16x8 __attribute__((ext_vector_type(8)));
typedef float  f32x4 __attribute__((ext_vector_type(4)));

#define MFMA32(A, B, C) __builtin_amdgcn_mfma_f32_16x16x32_bf16((A), (B), (C), 0, 0, 0)

static constexpr long QOFF  = 0;
static constexpr long KOFF  = 8388608;
static constexpr long VOFF  = 16777216;
static constexpr long FOFF  = 25165824;   // xb during gemm0, Of afterwards
static constexpr long WQOFF = 33554432;
static constexpr long WOOFF = 39845888;

// q scale: 1/sqrt(1024) * log2(e)  (softmax in exp2 domain)
#define QSCALE 0.045084222f

__device__ __forceinline__ void gl16(const bf16* g, bf16* l) {
  __builtin_amdgcn_global_load_lds((const __attribute__((address_space(1))) void*)g,
                                   (__attribute__((address_space(3))) void*)l, 16, 0, 0);
}

__device__ __forceinline__ f32x4 mfma16(bf16x4 a, bf16x4 b, f32x4 c) {
  asm("v_mfma_f32_16x16x16_bf16 %0, %1, %2, %0" : "+v"(c) : "v"(a), "v"(b));
  return c;
}

__device__ __forceinline__ float exp2fast(float x) {
#if __has_builtin(__builtin_amdgcn_exp2f)
  return __builtin_amdgcn_exp2f(x);
#else
  return exp2f(x);
#endif
}

__device__ __forceinline__ float max3f(float a, float b, float c) {
  return fmaxf(fmaxf(a, b), c);   // clang fuses to v_max3_f32
}

// one dispatch: 1048576 chunks of 8 f32 -> bf16
__global__ __launch_bounds__(256)
void cvt_all(const float* __restrict__ x, const float* __restrict__ wq,
             const float* __restrict__ wo, bf16* __restrict__ xb,
             bf16* __restrict__ wqb, bf16* __restrict__ wob) {
  const int i = blockIdx.x * 256 + threadIdx.x;
  const float* in; bf16* out; long j;
  if (i < 524288)      { in = x;  out = xb;  j = i; }
  else if (i < 917504) { in = wq; out = wqb; j = i - 524288; }
  else                 { in = wo; out = wob; j = i - 917504; }
  const f32x4 v0 = *(const f32x4*)(in + j * 8);
  const f32x4 v1 = *(const f32x4*)(in + j * 8 + 4);
  bf16x8 o;
#pragma unroll
  for (int k = 0; k < 4; ++k) { o[k] = (bf16)v0[k]; o[k + 4] = (bf16)v1[k]; }
  *(bf16x8*)(out + j * 8) = o;
}

// C[M,N] = A[M,K] * B[N,K]^T, K=1024, bf16 inputs. 128x128 tile, BK=32, 4 waves.
// Single-barrier double-buffer; 3 blocks/CU.
template <int MODE> // 0: qkv scatter epilogue; 1: f32+bias epilogue
__global__ __launch_bounds__(256, 3)
void gemm_bt(const bf16* __restrict__ Ag, const bf16* __restrict__ Bg,
             float* __restrict__ outp, const float* __restrict__ bias,
             char* __restrict__ wsp)
{
  constexpr int K  = 1024;
  constexpr int NT = K / 32;
  const int bm = blockIdx.y, bn = blockIdx.x;
  const int tid  = threadIdx.x;
  const int lane = tid & 63;
  const int l15  = lane & 15, g = lane >> 4;
  const int wave = tid >> 6;
  const int wr = wave >> 1, wc = wave & 1;

  __shared__ __align__(16) bf16 Ab[2][128 * 40];
  __shared__ __align__(16) bf16 Bb[2][128 * 40];

  const int r  = tid >> 1;
  const int c0 = (tid & 1) * 16;

  const bf16* ap = Ag + (long)(bm * 128 + r) * K + c0;
  const bf16* bp = Bg + (long)(bn * 128 + r) * K + c0;

  bf16x8 a0, a1, b0, b1;
  f32x4 acc[4][4] = {};

  auto load_regs = [&](int t) {
    a0 = *(const bf16x8*)(ap + t * 32);
    a1 = *(const bf16x8*)(ap + t * 32 + 8);
    b0 = *(const bf16x8*)(bp + t * 32);
    b1 = *(const bf16x8*)(bp + t * 32 + 8);
  };
  auto store_lds = [&](int buf) {
    *(bf16x8*)&Ab[buf][r * 40 + c0]     = a0;
    *(bf16x8*)&Ab[buf][r * 40 + c0 + 8] = a1;
    *(bf16x8*)&Bb[buf][r * 40 + c0]     = b0;
    *(bf16x8*)&Bb[buf][r * 40 + c0 + 8] = b1;
  };

  load_regs(0);
  store_lds(0);
  __syncthreads();

#pragma unroll 2
  for (int t = 0; t < NT; ++t) {
    if (t + 1 < NT) load_regs(t + 1);   // global->reg issue for next tile
    const int buf = t & 1;
    bf16x8 af[4], bfv[4];
#pragma unroll
    for (int mf = 0; mf < 4; ++mf)
      af[mf] = *(const bf16x8*)&Ab[buf][(wr * 64 + mf * 16 + l15) * 40 + g * 8];
#pragma unroll
    for (int nf = 0; nf < 4; ++nf)
      bfv[nf] = *(const bf16x8*)&Bb[buf][(wc * 64 + nf * 16 + l15) * 40 + g * 8];
#pragma unroll
    for (int mf = 0; mf < 4; ++mf)
#pragma unroll
      for (int nf = 0; nf < 4; ++nf)
        acc[mf][nf] = MFMA32(af[mf], bfv[nf], acc[mf][nf]);
    if (t + 1 < NT) store_lds((t + 1) & 1);  // write the non-read buffer
    __syncthreads();                         // single barrier per K-step
  }

  // C/D layout: col = lane&15, row = (lane>>4)*4 + reg
  if constexpr (MODE == 0) {
    bf16* Qb = (bf16*)(wsp + QOFF);
    bf16* Kb = (bf16*)(wsp + KOFF);
    bf16* Vw = (bf16*)(wsp + VOFF);
#pragma unroll
    for (int nf = 0; nf < 4; ++nf) {
      const int colb = bn * 128 + wc * 64 + nf * 16 + l15; // e in [0,3072)
      const int s = colb >> 10;          // 0:q 1:k 2:v
      const int h = (colb >> 6) & 15;
      const int d = colb & 63;
#pragma unroll
      for (int mf = 0; mf < 4; ++mf) {
#pragma unroll
        for (int rr = 0; rr < 4; ++rr) {
          const int rowg = bm * 128 + wr * 64 + mf * 16 + g * 4 + rr;
          const int bb = rowg >> 11, li = rowg & 2047;
          const float v = acc[mf][nf][rr];
          if (s == 0) {
            Qb[(long)((bb * 16 + h) * 2048 + li) * 64 + d] = (bf16)(v * QSCALE);
          } else if (s == 1) {
            const int sw = (((d >> 3) ^ (li & 7)) << 3) | (d & 7);
            Kb[(long)((bb * 16 + h) * 2048 + li) * 64 + sw] = (bf16)v;
          } else {
            const int lc = li & 63;
            const int sw = (((lc >> 3) ^ (d & 7)) << 3) | (lc & 7);
            Vw[(long)(bb * 16 + h) * 131072 + (li >> 6) * 4096 + d * 64 + sw] = (bf16)v;
          }
        }
      }
    }
  } else {
#pragma unroll
    for (int nf = 0; nf < 4; ++nf) {
      const int colg = bn * 128 + wc * 64 + nf * 16 + l15;
      const float bv = bias[colg];
#pragma unroll
      for (int mf = 0; mf < 4; ++mf) {
#pragma unroll
        for (int rr = 0; rr < 4; ++rr) {
          const int rowg = bm * 128 + wr * 64 + mf * 16 + g * 4 + rr;
          outp[(long)rowg * 1024 + colg] = acc[mf][nf][rr] + bv;
        }
      }
    }
  }
}

// Flash attention, swapped-operand, pipelined: S(t+1) MFMAs issued before
// softmax(t). K staged 2-ahead, V 1-ahead. Online defer-max softmax (guard).
// T5: setprio(1) around the S and PV MFMA clusters.
__global__ __launch_bounds__(256, 4)
void attn_fwd(const bf16* __restrict__ Q, const bf16* __restrict__ Kw,
              const bf16* __restrict__ Vw, bf16* __restrict__ Of)
{
  const int bid  = blockIdx.x;
  const int slot = bid >> 3;
  const int bh   = (bid & 7) * 4 + (slot >> 5);
  const int qt   = slot & 31;
  const int lane = threadIdx.x & 63;
  const int wave = threadIdx.x >> 6;
  const int l15  = lane & 15, g = lane >> 4;

  const bf16* Qh = Q  + (long)bh * 131072;
  const bf16* Ks = Kw + (long)bh * 131072;
  const bf16* Vs = Vw + (long)bh * 131072;

  __shared__ __align__(16) bf16 Klds[2][4096];
  __shared__ __align__(16) bf16 Vlds[2][4096];

  const int q0 = qt * 64 + wave * 16;

  bf16x8 qf[2];
#pragma unroll
  for (int ds = 0; ds < 2; ++ds)
    qf[ds] = *(const bf16x8*)(Qh + (q0 + l15) * 64 + ds * 32 + g * 8);

  auto stageK = [&](int t, int buf) {
    const bf16* sk = Ks + t * 4096 + wave * 1024 + lane * 8;
    gl16(sk,       &Klds[buf][wave * 1024]);
    gl16(sk + 512, &Klds[buf][wave * 1024 + 512]);
  };
  auto stageV = [&](int t, int buf) {
    const bf16* sv = Vs + t * 4096 + wave * 1024 + lane * 8;
    gl16(sv,       &Vlds[buf][wave * 1024]);
    gl16(sv + 512, &Vlds[buf][wave * 1024 + 512]);
  };

  f32x4 o[4] = {};
  float m = -1e30f, ps = 0.f;
  f32x4 sfA[4], sfB[4];

#define COMPUTE_S(BUF, SF) do {                                               \
  __builtin_amdgcn_s_setprio(1);                                              \
  _Pragma("unroll")                                                           \
  for (int kg = 0; kg < 4; ++kg) {                                            \
    SF[kg] = f32x4{0.f, 0.f, 0.f, 0.f};                                       \
    _Pragma("unroll")                                                         \
    for (int ds = 0; ds < 2; ++ds) {                                          \
      const bf16x8 kf = *(const bf16x8*)                                      \
        &Klds[BUF][(kg * 16 + l15) * 64 + (((ds * 4 + g) ^ (l15 & 7)) << 3)]; \
      SF[kg] = MFMA32(kf, qf[ds], SF[kg]);                                    \
    }                                                                         \
  }                                                                           \
  __builtin_amdgcn_s_setprio(0);                                              \
} while (0)

#define ATTN_BODY(T, SFC, SFN) do {                                           \
  if ((T) <= 29) stageK((T) + 2, (T) & 1);                                    \
  if ((T) <= 30) stageV((T) + 1, ((T) + 1) & 1);                              \
  if ((T) <= 30) COMPUTE_S(((T) + 1) & 1, SFN);                               \
  const float t0 = max3f(SFC[0][0], SFC[0][1], SFC[0][2]);                    \
  const float t1 = max3f(SFC[0][3], SFC[1][0], SFC[1][1]);                    \
  const float t2 = max3f(SFC[1][2], SFC[1][3], SFC[2][0]);                    \
  const float t3 = max3f(SFC[2][1], SFC[2][2], SFC[2][3]);                    \
  const float t4 = max3f(SFC[3][0], SFC[3][1], SFC[3][2]);                    \
  float tm = fmaxf(max3f(t0, t1, t2), max3f(t3, t4, SFC[3][3]));              \
  tm = fmaxf(tm, __shfl_xor(tm, 16));                                         \
  tm = fmaxf(tm, __shfl_xor(tm, 32));                                         \
  if (!__all(tm <= m + 8.f)) {                                                \
    const float nm = fmaxf(m, tm);                                            \
    const float al = exp2fast(m - nm);                                        \
    m = nm;                                                                   \
    ps *= al;                                                                 \
    _Pragma("unroll")                                                         \
    for (int dg = 0; dg < 4; ++dg)                                            \
      _Pragma("unroll")                                                       \
      for (int rr = 0; rr < 4; ++rr) o[dg][rr] *= al;                         \
  }                                                                           \
  bf16x4 pa[4];                                                               \
  float rs0 = 0.f, rs1 = 0.f, rs2 = 0.f, rs3 = 0.f;                           \
  _Pragma("unroll")                                                           \
  for (int kg = 0; kg < 4; ++kg) {                                            \
    const float p0 = exp2fast(SFC[kg][0] - m);                                \
    const float p1 = exp2fast(SFC[kg][1] - m);                                \
    const float p2 = exp2fast(SFC[kg][2] - m);                                \
    const float p3 = exp2fast(SFC[kg][3] - m);                                \
    rs0 += p0; rs1 += p1; rs2 += p2; rs3 += p3;                               \
    pa[kg][0] = (bf16)p0; pa[kg][1] = (bf16)p1;                               \
    pa[kg][2] = (bf16)p2; pa[kg][3] = (bf16)p3;                               \
  }                                                                           \
  ps += (rs0 + rs1) + (rs2 + rs3);                                            \
  __builtin_amdgcn_s_setprio(1);                                              \
  _Pragma("unroll")                                                           \
  for (int kg = 0; kg < 4; ++kg)                                              \
    _Pragma("unroll")                                                         \
    for (int dg = 0; dg < 4; ++dg) {                                          \
      const bf16x4 vb = *(const bf16x4*)                                      \
        &Vlds[(T) & 1][(dg * 16 + l15) * 64 +                                 \
                       (((2 * kg + (g >> 1)) ^ (l15 & 7)) << 3) +             \
                       ((g & 1) << 2)];                                       \
      o[dg] = mfma16(vb, pa[kg], o[dg]);                                      \
    }                                                                         \
  __builtin_amdgcn_s_setprio(0);                                              \
  __syncthreads();                                                            \
} while (0)

  // prologue: K0,V0 staged+drained; S(0) computed; K1 staged+drained
  stageK(0, 0);
  stageV(0, 0);
  __syncthreads();
  stageK(1, 1);
  COMPUTE_S(0, sfA);
  __syncthreads();

#pragma unroll 1
  for (int tp = 0; tp < 32; tp += 2) {
    ATTN_BODY(tp, sfA, sfB);
    ATTN_BODY(tp + 1, sfB, sfA);
  }

#undef ATTN_BODY
#undef COMPUTE_S

  ps += __shfl_xor(ps, 16);
  ps += __shfl_xor(ps, 32);
  const float inv = 1.f / ps;

  const int b = bh >> 4, h = bh & 15;
#pragma unroll
  for (int dg = 0; dg < 4; ++dg) {
    bf16x4 ov;
#pragma unroll
    for (int rr = 0; rr < 4; ++rr) ov[rr] = (bf16)(o[dg][rr] * inv);
    *(bf16x4*)(Of + (long)(b * 2048 + q0 + l15) * 1024 + h * 64 + dg * 16 + g * 4) = ov;
  }
}

extern "C" void kernel_launch(void* const* d_in, const int* in_sizes, int n_in,
                              void* d_out, int out_size, void* d_ws, size_t ws_size,
                              hipStream_t stream)
{
  (void)in_sizes; (void)n_in; (void)out_size; (void)ws_size;
  const float* x     = (const float*)d_in[0];
  const float* w_qkv = (const float*)d_in[1];
  const float* w_out = (const float*)d_in[2];
  const float* b_out = (const float*)d_in[3];
  float* out = (float*)d_out;
  char*  ws  = (char*)d_ws;

  bf16* Qb  = (bf16*)(ws + QOFF);
  bf16* Kb  = (bf16*)(ws + KOFF);
  bf16* Vw  = (bf16*)(ws + VOFF);
  bf16* xb  = (bf16*)(ws + FOFF);
  bf16* Ofb = (bf16*)(ws + FOFF);   // reuses xb region after gemm0 completes
  bf16* wqb = (bf16*)(ws + WQOFF);
  bf16* wob = (bf16*)(ws + WOOFF);

  cvt_all<<<dim3(4096), 256, 0, stream>>>(x, w_qkv, w_out, xb, wqb, wob);
  gemm_bt<0><<<dim3(24, 32), 256, 0, stream>>>(xb, wqb, nullptr, nullptr, ws);
  attn_fwd<<<dim3(1024), 256, 0, stream>>>(Qb, Kb, Vw, Ofb);
  gemm_bt<1><<<dim3(8, 32), 256, 0, stream>>>(Ofb, wob, out, b_out, ws);
}